// Round 14
// baseline (229.178 us; speedup 1.0000x reference)
//
#include <hip/hip_runtime.h>

typedef unsigned short u16;
typedef unsigned int   u32;
typedef __attribute__((ext_vector_type(8))) short bf16x8;
typedef __attribute__((ext_vector_type(4))) float f32x4;

// ---------- bf16 helpers (manual, RNE) ----------
__device__ __forceinline__ u16 f2bf(float f) {
    u32 u = __float_as_uint(f);
    u += 0x7fffu + ((u >> 16) & 1u);
    return (u16)(u >> 16);
}
__device__ __forceinline__ float bf2f(u16 s) {
    return __uint_as_float(((u32)s) << 16);
}
__device__ __forceinline__ u32 pack2bf(float f0, float f1) {
    return (u32)f2bf(f0) | ((u32)f2bf(f1) << 16);
}
// HW packed conversion (validated on P/ctx/x paths only — NOT upstream of
// the exp(10*cos-10) amplifier; see R13 post-mortem)
__device__ __forceinline__ u32 cvtpk2bf(float f0, float f1) {
    u32 r;
    asm("v_cvt_pk_bf16_f32 %0, %1, %2" : "=v"(r) : "v"(f0), "v"(f1));
    return r;
}

__device__ __forceinline__ void gload_lds16(const void* g, void* l) {
    __builtin_amdgcn_global_load_lds(
        (const __attribute__((address_space(1))) u32*)g,
        (__attribute__((address_space(3))) u32*)l, 16, 0, 0);
}

// =======================================================================
// fp32 -> bf16 converters
// =======================================================================
__global__ __launch_bounds__(256)
void conv_bf16(const float* __restrict__ src, u16* __restrict__ dst, int n8)
{
    const int i = blockIdx.x * 256 + threadIdx.x;   // 8 elements per thread
    if (i < n8) {
        const float4 a = ((const float4*)src)[2*i];
        const float4 b = ((const float4*)src)[2*i + 1];
        ((uint4*)dst)[i] = make_uint4(pack2bf(a.x,a.y), pack2bf(a.z,a.w),
                                      pack2bf(b.x,b.y), pack2bf(b.z,b.w));
    }
}

// w_qkv [2304][768]: keep q rows 0..767 and v rows 1536..2303 -> wqv [1536][768]
__global__ __launch_bounds__(256)
void conv_wqv(const float* __restrict__ w, u16* __restrict__ dst)
{
    const int i = blockIdx.x * 256 + threadIdx.x;   // chunk of 8, 96 chunks/row
    const int row = i / 96;
    const int cc  = (i - row * 96) * 8;
    const int srow = row + (row >= 768 ? 768 : 0);
    const float4 a = *(const float4*)&w[(size_t)srow*768 + cc];
    const float4 b = *(const float4*)&w[(size_t)srow*768 + cc + 4];
    *(uint4*)&dst[(size_t)row*768 + cc] =
        make_uint4(pack2bf(a.x,a.y), pack2bf(a.z,a.w), pack2bf(b.x,b.y), pack2bf(b.z,b.w));
}

// =======================================================================
// Shared MFMA GEMM core: C[128x128] tile, K=768, bf16 A[.,768] x B[.,768]^T.
// BK=64, 4 waves (2x2), 16x16x32 MFMA, global_load_lds + XOR-swizzled LDS.
// acc[mi][nj]: D rows (regs) follow A-side tile mi, D cols (lane&15) follow
// B-side tile nj.
// =======================================================================
__device__ __forceinline__ void mfma_gemm_core(
    const char* __restrict__ Arow0,   // &A[a0][0] as bytes (row stride 1536)
    const char* __restrict__ Brow0,   // &B[b0][0] as bytes
    u16* As, u16* Bs, const int tid, f32x4 acc[4][4])
{
    const int l  = tid & 63, w = tid >> 6;
    const int wr = w >> 1,  wc = w & 1;
    char* Asb = (char*)As;
    char* Bsb = (char*)Bs;
    const int co = 16 * ((l & 7) ^ (l >> 3));       // swizzled global byte col
    const size_t rstep = (size_t)(l >> 3) * 1536;
    const int rsw = (l & 7) << 4;                   // read-side XOR

    for (int k0 = 0; k0 < 1536; k0 += 128) {        // 12 K-steps of 64 bf16
        #pragma unroll
        for (int i = 0; i < 4; ++i) {
            const int rb = i*32 + w*8;
            gload_lds16(Arow0 + (size_t)rb*1536 + rstep + k0 + co, Asb + i*4096 + w*1024);
            gload_lds16(Brow0 + (size_t)rb*1536 + rstep + k0 + co, Bsb + i*4096 + w*1024);
        }
        __syncthreads();
        bf16x8 af[2][4], bfr[2][4];
        #pragma unroll
        for (int kk = 0; kk < 2; ++kk) {
            const int coff = (kk*64 + ((l >> 4) << 4)) ^ rsw;
            #pragma unroll
            for (int mi = 0; mi < 4; ++mi) {
                const int rowA = wr*64 + mi*16 + (l & 15);
                af[kk][mi]  = *(const bf16x8*)(Asb + rowA*128 + coff);
                const int rowB = wc*64 + mi*16 + (l & 15);
                bfr[kk][mi] = *(const bf16x8*)(Bsb + rowB*128 + coff);
            }
        }
        #pragma unroll
        for (int mi = 0; mi < 4; ++mi)
            #pragma unroll
            for (int nj = 0; nj < 4; ++nj) {
                acc[mi][nj] = __builtin_amdgcn_mfma_f32_16x16x32_bf16(
                                  af[0][mi], bfr[0][nj], acc[mi][nj], 0, 0, 0);
                acc[mi][nj] = __builtin_amdgcn_mfma_f32_16x16x32_bf16(
                                  af[1][mi], bfr[1][nj], acc[mi][nj], 0, 0, 0);
            }
        __syncthreads();
    }
}

// =======================================================================
// K0: q/v projection + FUSED q-normalize.
// q-blocks (bj<6): OPERAND-SWAPPED — A = wqv rows (q-cols, d on regs),
//   B = x rows (n on lanes). Norm = 16 local FMAs + 2 shfl_xor (quarters);
//   writes qn bf16 [bh][n][d] via packed uint2 (manual RNE pack2bf).
// v-blocks (bj>=6): A = x rows, B = wqv rows; vbfT [bh][d][m] packed uint2.
// =======================================================================
__global__ __launch_bounds__(256)
void gemm_qkv_mfma(const u16* __restrict__ xbf, const u16* __restrict__ wqv,
                   u16* __restrict__ qnbf, u16* __restrict__ vbfT)
{
    __shared__ u16 As[128*64];
    __shared__ u16 Bs[128*64];
    const int m0 = blockIdx.x * 128;
    const int bj = blockIdx.y;
    const int tid = threadIdx.x;
    f32x4 acc[4][4];
    #pragma unroll
    for (int i = 0; i < 4; ++i)
        #pragma unroll
        for (int j = 0; j < 4; ++j) acc[i][j] = (f32x4){0.f,0.f,0.f,0.f};

    const char* Aro = (bj < 6) ? (const char*)wqv + (size_t)bj*128*1536
                               : (const char*)xbf + (size_t)m0*1536;
    const char* Bro = (bj < 6) ? (const char*)xbf + (size_t)m0*1536
                               : (const char*)wqv + (size_t)bj*128*1536;
    mfma_gemm_core(Aro, Bro, As, Bs, tid, acc);

    const int l = tid & 63, w = tid >> 6;
    const int wr = w >> 1, wc = w & 1;
    if (bj < 6) {
        const int h = 2*bj + wr;                   // A-side wave block = head
        #pragma unroll
        for (int nj = 0; nj < 4; ++nj) {
            const int m = m0 + wc*64 + nj*16 + (l & 15);
            const int b_ = m >> 8, n_ = m & 255;
            float s = 0.f;
            #pragma unroll
            for (int mi = 0; mi < 4; ++mi)
                #pragma unroll
                for (int rr = 0; rr < 4; ++rr)
                    s = fmaf(acc[mi][nj][rr], acc[mi][nj][rr], s);
            s += __shfl_xor(s, 16);
            s += __shfl_xor(s, 32);                // 4 quarters cover all 64 d
            const float inv = 1.0f / (sqrtf(s) + 1e-8f);
            u16* row = qnbf + ((((size_t)b_*12 + h) << 8) + n_)*64;
            #pragma unroll
            for (int mi = 0; mi < 4; ++mi) {
                const int d0 = mi*16 + ((l >> 4) << 2);
                uint2 o = make_uint2(pack2bf(acc[mi][nj][0]*inv, acc[mi][nj][1]*inv),
                                     pack2bf(acc[mi][nj][2]*inv, acc[mi][nj][3]*inv));
                *(uint2*)&row[d0] = o;
            }
        }
    } else {
        const int colb = (bj - 6)*128 + wc*64;
        const int rbase = m0 + wr*64 + ((l >> 4) << 2);
        #pragma unroll
        for (int mi = 0; mi < 4; ++mi)
            #pragma unroll
            for (int nj = 0; nj < 4; ++nj) {
                const int col = colb + nj*16 + (l & 15);
                const int h = col >> 6, d = col & 63;
                const int m = rbase + mi*16;        // rows m..m+3 (consecutive)
                const int b_ = m >> 8, n_ = m & 255;
                uint2 o = make_uint2(pack2bf(acc[mi][nj][0], acc[mi][nj][1]),
                                     pack2bf(acc[mi][nj][2], acc[mi][nj][3]));
                *(uint2*)&vbfT[(((size_t)b_*12 + h)*64 + d)*256 + n_] = o;
            }
    }
}

// =======================================================================
// K5: out = ctx @ w_proj^T + b_proj — OPERAND-SWAPPED: A = wpb rows
// (out-cols on regs), B = ctxc rows (out-rows on lanes). float4 stores.
// =======================================================================
__global__ __launch_bounds__(256)
void gemm_proj_mfma(const u16* __restrict__ ctxb, const u16* __restrict__ wpb,
                    const float* __restrict__ bias, float* __restrict__ out)
{
    __shared__ u16 As[128*64];
    __shared__ u16 Bs[128*64];
    const int m0 = blockIdx.x * 128;
    const int n0 = blockIdx.y * 128;
    const int tid = threadIdx.x;
    f32x4 acc[4][4];
    #pragma unroll
    for (int i = 0; i < 4; ++i)
        #pragma unroll
        for (int j = 0; j < 4; ++j) acc[i][j] = (f32x4){0.f,0.f,0.f,0.f};

    mfma_gemm_core((const char*)wpb + (size_t)n0*1536,
                   (const char*)ctxb + (size_t)m0*1536,
                   As, Bs, tid, acc);

    const int l = tid & 63, w = tid >> 6;
    const int wr = w >> 1, wc = w & 1;
    #pragma unroll
    for (int nj = 0; nj < 4; ++nj) {
        const int m = m0 + wc*64 + nj*16 + (l & 15);
        #pragma unroll
        for (int mi = 0; mi < 4; ++mi) {
            const int c0 = n0 + wr*64 + mi*16 + ((l >> 4) << 2);
            const float4 bv = *(const float4*)&bias[c0];
            float4 o = make_float4(acc[mi][nj][0] + bv.x, acc[mi][nj][1] + bv.y,
                                   acc[mi][nj][2] + bv.z, acc[mi][nj][3] + bv.w);
            *(float4*)&out[(size_t)m*768 + c0] = o;
        }
    }
}

// =======================================================================
// K2: K[n][m] = exp(10*cos(n,m) - 10) off-diag, 0 on diag. bf16 out.
// MFMA on qn tiles; OPERAND-SWAPPED epilogue: mfma(bfr, af) puts gc on
// regs, gr on lanes -> packed uint2 K stores (manual RNE pack2bf).
// =======================================================================
__global__ __launch_bounds__(256)
void cost_kernel(const u16* __restrict__ qnbf, u16* __restrict__ Kmat)
{
    __shared__ u16 Qa[128*64];     // [row][64 k] bf16, slot s holds global slot s^(row&7)
    __shared__ u16 Qb[128*64];
    const int bh = blockIdx.y;
    const int tr = (blockIdx.x >> 1) * 128;
    const int tc = (blockIdx.x & 1) * 128;
    const char* qb = (const char*)(qnbf + (size_t)bh * 16384);
    const int tid = threadIdx.x;
    const int l = tid & 63, w = tid >> 6;
    const int wr = w >> 1, wc = w & 1;

    // ---- stage both tiles: 4 issues/wave/array; rows 8*(i*4+w)+(l>>3)
    {
        const int co = ((l & 7) ^ (l >> 3)) << 4;   // inverse-swizzled source slot
        const int rl = l >> 3;
        #pragma unroll
        for (int i = 0; i < 4; ++i) {
            const int ch = i*4 + w;                 // chunk 0..15
            gload_lds16(qb + (size_t)(tr + ch*8 + rl)*128 + co, (char*)Qa + ch*1024);
            gload_lds16(qb + (size_t)(tc + ch*8 + rl)*128 + co, (char*)Qb + ch*1024);
        }
    }
    __syncthreads();

    f32x4 acc[4][4];
    #pragma unroll
    for (int i = 0; i < 4; ++i)
        #pragma unroll
        for (int j = 0; j < 4; ++j) acc[i][j] = (f32x4){0.f,0.f,0.f,0.f};

    bf16x8 af[2][4], bfr[2][4];
    #pragma unroll
    for (int kk = 0; kk < 2; ++kk) {
        const int kb = kk*64 + ((l >> 4) << 4);
        #pragma unroll
        for (int f = 0; f < 4; ++f) {
            const int ra = wr*64 + f*16 + (l & 15);
            af[kk][f]  = *(const bf16x8*)((char*)Qa + ra*128 + (kb ^ ((ra & 7) << 4)));
            const int rb = wc*64 + f*16 + (l & 15);
            bfr[kk][f] = *(const bf16x8*)((char*)Qb + rb*128 + (kb ^ ((rb & 7) << 4)));
        }
    }
    // swapped: A-operand = bfr (tc side -> regs), B-operand = af (tr side -> lanes)
    #pragma unroll
    for (int mi = 0; mi < 4; ++mi)
        #pragma unroll
        for (int nj = 0; nj < 4; ++nj) {
            acc[mi][nj] = __builtin_amdgcn_mfma_f32_16x16x32_bf16(
                              bfr[0][nj], af[0][mi], acc[mi][nj], 0, 0, 0);
            acc[mi][nj] = __builtin_amdgcn_mfma_f32_16x16x32_bf16(
                              bfr[1][nj], af[1][mi], acc[mi][nj], 0, 0, 0);
        }

    // ---- epilogue: exp(10*s - 10), diag -> 0, packed bf16 store
    u16* Kb = Kmat + (size_t)bh * 65536;
    #pragma unroll
    for (int mi = 0; mi < 4; ++mi)
        #pragma unroll
        for (int nj = 0; nj < 4; ++nj) {
            const int gr  = tr + wr*64 + mi*16 + (l & 15);
            const int gc0 = tc + wc*64 + nj*16 + ((l >> 4) << 2);
            float km[4];
            #pragma unroll
            for (int rr = 0; rr < 4; ++rr) {
                const float s = acc[mi][nj][rr];
                km[rr] = (gr == gc0 + rr) ? 0.f : __expf(fmaf(10.f, s, -10.f));
            }
            *(uint2*)&Kb[(size_t)gr * 256 + gc0] =
                make_uint2(pack2bf(km[0], km[1]), pack2bf(km[2], km[3]));
        }
}

// =======================================================================
// K3 (split A): Sinkhorn iterations + Tmax only. (unchanged, R12-validated)
// =======================================================================
__global__ __launch_bounds__(512, 2)
void sinkhorn_kernel(const u16* __restrict__ Kmat, float* __restrict__ ubuf,
                     float* __restrict__ vbuf, float* __restrict__ tmaxbuf)
{
    __shared__ __align__(16) float xv[256];
    __shared__ __align__(16) float usave[256];
    __shared__ __align__(16) u16   xbf[256];
    __shared__ float pmax[8];
    const int bh  = blockIdx.x;
    const int tid = threadIdx.x;
    const int l = tid & 63, w = tid >> 6;
    const int rowb = w * 32;
    const char* Kg = (const char*)(Kmat + (size_t)bh * 65536);

    bf16x8 kf[2][8];
    {
        const char* kb0 = Kg + (size_t)(rowb + (l & 15)) * 512 + ((l >> 4) << 4);
        #pragma unroll
        for (int t = 0; t < 2; ++t)
            #pragma unroll
            for (int ks = 0; ks < 8; ++ks)
                kf[t][ks] = *(const bf16x8*)(kb0 + t*8192 + ks*64);
    }
    if (tid < 256) xbf[tid] = 0x3f80;    // bf16(1.0)
    __syncthreads();

    for (int it = 0; it < 20; ++it) {
        f32x4 a0a = {0.f,0.f,0.f,0.f}, a0b = {0.f,0.f,0.f,0.f};
        f32x4 a1a = {0.f,0.f,0.f,0.f}, a1b = {0.f,0.f,0.f,0.f};
        #pragma unroll
        for (int ks = 0; ks < 4; ++ks) {
            const bf16x8 xf = *(const bf16x8*)((const char*)xbf + ks*64 + ((l >> 4) << 4));
            a0a = __builtin_amdgcn_mfma_f32_16x16x32_bf16(kf[0][ks], xf, a0a, 0, 0, 0);
            a1a = __builtin_amdgcn_mfma_f32_16x16x32_bf16(kf[1][ks], xf, a1a, 0, 0, 0);
        }
        #pragma unroll
        for (int ks = 4; ks < 8; ++ks) {
            const bf16x8 xf = *(const bf16x8*)((const char*)xbf + ks*64 + ((l >> 4) << 4));
            a0b = __builtin_amdgcn_mfma_f32_16x16x32_bf16(kf[0][ks], xf, a0b, 0, 0, 0);
            a1b = __builtin_amdgcn_mfma_f32_16x16x32_bf16(kf[1][ks], xf, a1b, 0, 0, 0);
        }
        float xn0[4], xn1[4];
        #pragma unroll
        for (int j = 0; j < 4; ++j) {
            xn0[j] = 0.00390625f * __builtin_amdgcn_rcpf(a0a[j] + a0b[j]);
            xn1[j] = 0.00390625f * __builtin_amdgcn_rcpf(a1a[j] + a1b[j]);
        }
        const u32 xp0 = cvtpk2bf(xn0[0], xn0[1]);
        const u32 xp1 = cvtpk2bf(xn0[2], xn0[3]);
        const u32 xp2 = cvtpk2bf(xn1[0], xn1[1]);
        const u32 xp3 = cvtpk2bf(xn1[2], xn1[3]);
        if ((l & 15) == 0) {
            const int r0 = rowb + ((l >> 4) << 2);
            *(uint2*)&xbf[r0]      = make_uint2(xp0, xp1);
            *(uint2*)&xbf[r0 + 16] = make_uint2(xp2, xp3);
            if (it == 18) {
                *(float4*)&usave[r0]      = make_float4(xn0[0], xn0[1], xn0[2], xn0[3]);
                *(float4*)&usave[r0 + 16] = make_float4(xn1[0], xn1[1], xn1[2], xn1[3]);
            }
            if (it == 19) {
                *(float4*)&xv[r0]      = make_float4(xn0[0], xn0[1], xn0[2], xn0[3]);
                *(float4*)&xv[r0 + 16] = make_float4(xn1[0], xn1[1], xn1[2], xn1[3]);
            }
        }
        __syncthreads();
    }

    {
        float mx0 = 0.f, mx1 = 0.f;
        #pragma unroll
        for (int ks = 0; ks < 8; ++ks) {
            const int mbase = ks*32 + ((l >> 4) << 3);
            const float4 va  = *(const float4*)&xv[mbase];
            const float4 vb4 = *(const float4*)&xv[mbase + 4];
            const float vv[8] = {va.x, va.y, va.z, va.w, vb4.x, vb4.y, vb4.z, vb4.w};
            #pragma unroll
            for (int j = 0; j < 8; ++j) {
                mx0 = fmaxf(mx0, bf2f((u16)kf[0][ks][j]) * vv[j]);
                mx1 = fmaxf(mx1, bf2f((u16)kf[1][ks][j]) * vv[j]);
            }
        }
        float mx = fmaxf(usave[rowb + (l & 15)] * mx0,
                         usave[rowb + 16 + (l & 15)] * mx1);
        #pragma unroll
        for (int off = 32; off > 0; off >>= 1) mx = fmaxf(mx, __shfl_xor(mx, off));
        if (l == 0) pmax[w] = mx;
    }
    __syncthreads();
    if (tid < 256) {
        ubuf[bh * 256 + tid] = usave[tid];
        vbuf[bh * 256 + tid] = xv[tid];
    }
    if (tid == 0) {
        float tm = pmax[0];
        #pragma unroll
        for (int i = 1; i < 8; ++i) tm = fmaxf(tm, pmax[i]);
        tmaxbuf[bh] = tm;
    }
}

// =======================================================================
// K4 (split B): P + PV. (unchanged, R12-validated)
// =======================================================================
__global__ __launch_bounds__(512, 2)
void pv_kernel(const u16* __restrict__ Kmat, const u16* __restrict__ vbfT,
               const float* __restrict__ ubuf, const float* __restrict__ vbuf,
               const float* __restrict__ tmaxbuf, u16* __restrict__ ctxc)
{
    __shared__ u16 Vt[64*256];       // 32 KB, slot s of row d holds global slot s^(d&7)
    __shared__ __align__(16) float xv[256];
    const int bh  = blockIdx.x;
    const int b_ = bh / 12, h_ = bh - b_*12;
    const int tid = threadIdx.x;
    const int l = tid & 63, w = tid >> 6;
    const int rowb = w * 32;
    const char* Kg = (const char*)(Kmat + (size_t)bh * 65536);

    {
        const char* src = (const char*)(vbfT + (size_t)bh * 16384);
        char* dst = (char*)Vt;
        const int s = l & 31;
        #pragma unroll
        for (int i = 0; i < 4; ++i) {
            const int d = i*16 + w*2 + (l >> 5);
            gload_lds16(src + d*512 + ((s ^ (d & 7)) << 4), dst + i*8192 + w*1024);
        }
    }
    if (tid < 256) xv[tid] = vbuf[bh*256 + tid];

    bf16x8 kf[2][8];
    {
        const char* kb0 = Kg + (size_t)(rowb + (l & 15)) * 512 + ((l >> 4) << 4);
        #pragma unroll
        for (int t = 0; t < 2; ++t)
            #pragma unroll
            for (int ks = 0; ks < 8; ++ks)
                kf[t][ks] = *(const bf16x8*)(kb0 + t*8192 + ks*64);
    }
    const float itmax = 1.0f / tmaxbuf[bh];
    const float u0 = ubuf[bh*256 + rowb + (l & 15)];
    const float u1 = ubuf[bh*256 + rowb + 16 + (l & 15)];
    __syncthreads();                 // Vt + xv resident

    u16* outp = ctxc + ((size_t)b_*256)*768 + h_*64;
    #pragma unroll
    for (int t = 0; t < 2; ++t) {
        const int rown = rowb + t*16 + (l & 15);
        const float an = (t == 0 ? u0 : u1) * itmax * 0.125f;
        float psum = 0.f;
        f32x4 acc0 = {0.f,0.f,0.f,0.f}, acc1 = {0.f,0.f,0.f,0.f};
        f32x4 acc2 = {0.f,0.f,0.f,0.f}, acc3 = {0.f,0.f,0.f,0.f};
        #pragma unroll
        for (int ks = 0; ks < 8; ++ks) {
            const int mbase = ks*32 + ((l >> 4) << 3);
            const float4 va  = *(const float4*)&xv[mbase];
            const float4 vb4 = *(const float4*)&xv[mbase + 4];
            const float vv[8] = {va.x, va.y, va.z, va.w, vb4.x, vb4.y, vb4.z, vb4.w};
            float p[8];
            #pragma unroll
            for (int j = 0; j < 8; ++j)
                p[j] = __expf(an * bf2f((u16)kf[t][ks][j]) * vv[j]);
            const int dj = rown - mbase;
            if (dj >= 0 && dj < 8) p[dj] = 1.13314845f;     // exp(0.125)
            psum += ((p[0]+p[1]) + (p[2]+p[3])) + ((p[4]+p[5]) + (p[6]+p[7]));
            uint4 pwv = make_uint4(cvtpk2bf(p[0], p[1]), cvtpk2bf(p[2], p[3]),
                                   cvtpk2bf(p[4], p[5]), cvtpk2bf(p[6], p[7]));
            const bf16x8 pf = *(const bf16x8*)&pwv;
            const int bc = ks*64 + ((l >> 4) << 4);
            {
                const int d = (l & 15);
                const bf16x8 vf = *(const bf16x8*)((char*)Vt + d*512 + (bc ^ ((d & 7) << 4)));
                acc0 = __builtin_amdgcn_mfma_f32_16x16x32_bf16(vf, pf, acc0, 0, 0, 0);
            }
            {
                const int d = 16 + (l & 15);
                const bf16x8 vf = *(const bf16x8*)((char*)Vt + d*512 + (bc ^ ((d & 7) << 4)));
                acc1 = __builtin_amdgcn_mfma_f32_16x16x32_bf16(vf, pf, acc1, 0, 0, 0);
            }
            {
                const int d = 32 + (l & 15);
                const bf16x8 vf = *(const bf16x8*)((char*)Vt + d*512 + (bc ^ ((d & 7) << 4)));
                acc2 = __builtin_amdgcn_mfma_f32_16x16x32_bf16(vf, pf, acc2, 0, 0, 0);
            }
            {
                const int d = 48 + (l & 15);
                const bf16x8 vf = *(const bf16x8*)((char*)Vt + d*512 + (bc ^ ((d & 7) << 4)));
                acc3 = __builtin_amdgcn_mfma_f32_16x16x32_bf16(vf, pf, acc3, 0, 0, 0);
            }
        }
        psum += __shfl_xor(psum, 16);
        psum += __shfl_xor(psum, 32);                  // 4 lanes/row summed
        const float is = 1.0f / psum;
        const int d0 = (l >> 4) << 2;
        uint2 o0 = make_uint2(cvtpk2bf(acc0[0]*is, acc0[1]*is), cvtpk2bf(acc0[2]*is, acc0[3]*is));
        uint2 o1 = make_uint2(cvtpk2bf(acc1[0]*is, acc1[1]*is), cvtpk2bf(acc1[2]*is, acc1[3]*is));
        uint2 o2 = make_uint2(cvtpk2bf(acc2[0]*is, acc2[1]*is), cvtpk2bf(acc2[2]*is, acc2[3]*is));
        uint2 o3 = make_uint2(cvtpk2bf(acc3[0]*is, acc3[1]*is), cvtpk2bf(acc3[2]*is, acc3[3]*is));
        u16* orow = outp + (size_t)rown*768;
        *(uint2*)&orow[d0]      = o0;
        *(uint2*)&orow[16 + d0] = o1;
        *(uint2*)&orow[32 + d0] = o2;
        *(uint2*)&orow[48 + d0] = o3;
    }
}

// =======================================================================
extern "C" void kernel_launch(void* const* d_in, const int* in_sizes, int n_in,
                              void* d_out, int out_size, void* d_ws, size_t ws_size,
                              hipStream_t stream)
{
    (void)in_sizes; (void)n_in; (void)out_size; (void)ws_size;
    const float* x      = (const float*)d_in[0];
    const float* w_qkv  = (const float*)d_in[1];
    const float* w_proj = (const float*)d_in[2];
    const float* b_proj = (const float*)d_in[3];
    float* out = (float*)d_out;

    char* w = (char*)d_ws;
    // workspace layout (bytes):
    u16*   xbf  = (u16*)  (w);                     //  25,165,824  x bf16 [16384][768]
    u16*   wqv  = (u16*)  (w + 25165824);          //   2,359,296  w q+v rows bf16 [1536][768]
    u16*   wpb  = (u16*)  (w + 27525120);          //   1,179,648  w_proj bf16 [768][768]
    u16*   qnbf = (u16*)  (w + 28704768);          //  25,165,824  qn bf16 [768][256][64]
    u16*   vbfT = (u16*)  (w + 79036416);          //  25,165,824  v^T bf16 [768][64][256]
    u16*   ctxc = (u16*)  (w + 104202240);         //  25,165,824  ctx bf16 [64][256][768]
    float* ub   = (float*)(w + 129368064);         //     786,432  u [768][256]
    float* vb   = (float*)(w + 130154496);         //     786,432  v [768][256]
    float* tmx  = (float*)(w + 130940928);         //       3,072  tmax [768]
    u16*   Km   = (u16*)  (w + 130944000);         // 100,663,296  K bf16 [768][256][256]
    // total ~231.6 MB

    conv_bf16      <<<dim3(6144),    256, 0, stream>>>(x, xbf, 1572864);
    conv_wqv       <<<dim3(576),     256, 0, stream>>>(w_qkv, wqv);
    conv_bf16      <<<dim3(288),     256, 0, stream>>>(w_proj, wpb, 73728);
    gemm_qkv_mfma  <<<dim3(128, 12), 256, 0, stream>>>(xbf, wqv, qnbf, vbfT);
    cost_kernel    <<<dim3(4, 768),  256, 0, stream>>>(qnbf, Km);
    sinkhorn_kernel<<<dim3(768),     512, 0, stream>>>(Km, ub, vb, tmx);
    pv_kernel      <<<dim3(768),     512, 0, stream>>>(Km, vbfT, ub, vb, tmx, ctxc);
    gemm_proj_mfma <<<dim3(128, 6),  256, 0, stream>>>(ctxc, wpb, b_proj, out);
}

// Round 15
// 215.857 us; speedup vs baseline: 1.0617x; 1.0617x over previous
//
#include <hip/hip_runtime.h>

typedef unsigned short u16;
typedef unsigned int   u32;
typedef __attribute__((ext_vector_type(8))) short bf16x8;
typedef __attribute__((ext_vector_type(4))) float f32x4;

// ---------- bf16 helpers (manual, RNE) ----------
__device__ __forceinline__ u16 f2bf(float f) {
    u32 u = __float_as_uint(f);
    u += 0x7fffu + ((u >> 16) & 1u);
    return (u16)(u >> 16);
}
__device__ __forceinline__ float bf2f(u16 s) {
    return __uint_as_float(((u32)s) << 16);
}
__device__ __forceinline__ u32 pack2bf(float f0, float f1) {
    return (u32)f2bf(f0) | ((u32)f2bf(f1) << 16);
}
// HW packed conversion (validated on P/ctx/x-iterate paths only — NOT
// upstream of the exp(10*cos-10) amplifier; see R13 post-mortem)
__device__ __forceinline__ u32 cvtpk2bf(float f0, float f1) {
    u32 r;
    asm("v_cvt_pk_bf16_f32 %0, %1, %2" : "=v"(r) : "v"(f0), "v"(f1));
    return r;
}

__device__ __forceinline__ void gload_lds16(const void* g, void* l) {
    __builtin_amdgcn_global_load_lds(
        (const __attribute__((address_space(1))) u32*)g,
        (__attribute__((address_space(3))) u32*)l, 16, 0, 0);
}

// =======================================================================
// Fused fp32 -> bf16 conversion for ALL three inputs (one launch):
//   chunk i in [0, 1572864): x [16384][768] -> xbf
//   next 147456 chunks:      w_qkv q-rows 0..767 + v-rows 1536..2303 -> wqv
//   next 73728 chunks:       w_proj [768][768] -> wpb
// Each chunk = 8 consecutive floats -> uint4 of 8 bf16 (RNE pack2bf).
// =======================================================================
__global__ __launch_bounds__(256)
void conv_all(const float* __restrict__ x, const float* __restrict__ wqkv,
              const float* __restrict__ wproj, u16* __restrict__ xbf,
              u16* __restrict__ wqv, u16* __restrict__ wpb)
{
    const int i = blockIdx.x * 256 + threadIdx.x;
    if (i < 1572864) {
        const float4 a = ((const float4*)x)[2*i];
        const float4 b = ((const float4*)x)[2*i + 1];
        ((uint4*)xbf)[i] = make_uint4(pack2bf(a.x,a.y), pack2bf(a.z,a.w),
                                      pack2bf(b.x,b.y), pack2bf(b.z,b.w));
    } else if (i < 1572864 + 147456) {
        const int j = i - 1572864;
        const int row = j / 96;
        const int cc  = (j - row * 96) * 8;
        const int srow = row + (row >= 768 ? 768 : 0);
        const float4 a = *(const float4*)&wqkv[(size_t)srow*768 + cc];
        const float4 b = *(const float4*)&wqkv[(size_t)srow*768 + cc + 4];
        *(uint4*)&wqv[(size_t)row*768 + cc] =
            make_uint4(pack2bf(a.x,a.y), pack2bf(a.z,a.w),
                       pack2bf(b.x,b.y), pack2bf(b.z,b.w));
    } else if (i < 1572864 + 147456 + 73728) {
        const int j = i - 1572864 - 147456;
        const float4 a = ((const float4*)wproj)[2*j];
        const float4 b = ((const float4*)wproj)[2*j + 1];
        ((uint4*)wpb)[j] = make_uint4(pack2bf(a.x,a.y), pack2bf(a.z,a.w),
                                      pack2bf(b.x,b.y), pack2bf(b.z,b.w));
    }
}

// =======================================================================
// Shared MFMA GEMM core: C[128x128] tile, K=768, bf16 A[.,768] x B[.,768]^T.
// BK=64, 4 waves (2x2), 16x16x32 MFMA, global_load_lds + XOR-swizzled LDS.
// =======================================================================
__device__ __forceinline__ void mfma_gemm_core(
    const char* __restrict__ Arow0,   // &A[m0][0] as bytes (row stride 1536)
    const char* __restrict__ Brow0,   // &B[n0][0] as bytes
    u16* As, u16* Bs, const int tid, f32x4 acc[4][4])
{
    const int l  = tid & 63, w = tid >> 6;
    const int wr = w >> 1,  wc = w & 1;
    char* Asb = (char*)As;
    char* Bsb = (char*)Bs;
    const int co = 16 * ((l & 7) ^ (l >> 3));       // swizzled global byte col
    const size_t rstep = (size_t)(l >> 3) * 1536;
    const int rsw = (l & 7) << 4;                   // read-side XOR

    for (int k0 = 0; k0 < 1536; k0 += 128) {        // 12 K-steps of 64 bf16
        #pragma unroll
        for (int i = 0; i < 4; ++i) {
            const int rb = i*32 + w*8;
            gload_lds16(Arow0 + (size_t)rb*1536 + rstep + k0 + co, Asb + i*4096 + w*1024);
            gload_lds16(Brow0 + (size_t)rb*1536 + rstep + k0 + co, Bsb + i*4096 + w*1024);
        }
        __syncthreads();
        bf16x8 af[2][4], bfr[2][4];
        #pragma unroll
        for (int kk = 0; kk < 2; ++kk) {
            const int coff = (kk*64 + ((l >> 4) << 4)) ^ rsw;
            #pragma unroll
            for (int mi = 0; mi < 4; ++mi) {
                const int rowA = wr*64 + mi*16 + (l & 15);
                af[kk][mi]  = *(const bf16x8*)(Asb + rowA*128 + coff);
                const int rowB = wc*64 + mi*16 + (l & 15);
                bfr[kk][mi] = *(const bf16x8*)(Bsb + rowB*128 + coff);
            }
        }
        #pragma unroll
        for (int mi = 0; mi < 4; ++mi)
            #pragma unroll
            for (int nj = 0; nj < 4; ++nj) {
                acc[mi][nj] = __builtin_amdgcn_mfma_f32_16x16x32_bf16(
                                  af[0][mi], bfr[0][nj], acc[mi][nj], 0, 0, 0);
                acc[mi][nj] = __builtin_amdgcn_mfma_f32_16x16x32_bf16(
                                  af[1][mi], bfr[1][nj], acc[mi][nj], 0, 0, 0);
            }
        __syncthreads();
    }
}

// =======================================================================
// K0: q/v projection + FUSED q-normalize. xbf [16384][768], wqv [1536][768].
// bj<6 -> q cols: each wave's 64 cols = one head (h = 2bj+wc); row-norm via
// 16-lane shfl_xor reduce over nj-frags; writes qn bf16 [bh][n][64] direct.
// bj>=6 -> v cols, written TRANSPOSED as vbfT [bh][d][m] bf16.
// (R12-exact — best-known-good configuration)
// =======================================================================
__global__ __launch_bounds__(256)
void gemm_qkv_mfma(const u16* __restrict__ xbf, const u16* __restrict__ wqv,
                   u16* __restrict__ qnbf, u16* __restrict__ vbfT)
{
    __shared__ u16 As[128*64];
    __shared__ u16 Bs[128*64];
    const int m0 = blockIdx.x * 128;
    const int bj = blockIdx.y;
    const int tid = threadIdx.x;
    f32x4 acc[4][4];
    #pragma unroll
    for (int i = 0; i < 4; ++i)
        #pragma unroll
        for (int j = 0; j < 4; ++j) acc[i][j] = (f32x4){0.f,0.f,0.f,0.f};

    mfma_gemm_core((const char*)xbf + (size_t)m0*1536,
                   (const char*)wqv + (size_t)bj*128*1536,
                   As, Bs, tid, acc);

    const int l = tid & 63, w = tid >> 6;
    const int wr = w >> 1, wc = w & 1;
    const int rbase = m0 + wr*64 + ((l >> 4) << 2);
    if (bj < 6) {
        const int h = 2*bj + wc;                   // wave's 64 cols = head h
        #pragma unroll
        for (int mi = 0; mi < 4; ++mi)
            #pragma unroll
            for (int rr = 0; rr < 4; ++rr) {
                float s =      acc[mi][0][rr]*acc[mi][0][rr];
                s = fmaf(acc[mi][1][rr], acc[mi][1][rr], s);
                s = fmaf(acc[mi][2][rr], acc[mi][2][rr], s);
                s = fmaf(acc[mi][3][rr], acc[mi][3][rr], s);
                #pragma unroll
                for (int off = 1; off < 16; off <<= 1) s += __shfl_xor(s, off);
                const float inv = 1.0f / (sqrtf(s) + 1e-8f);
                const int m = rbase + mi*16 + rr;
                const int b_ = m >> 8, n_ = m & 255;
                u16* row = qnbf + ((((size_t)b_*12 + h) << 8) + n_)*64;
                #pragma unroll
                for (int nj = 0; nj < 4; ++nj)
                    row[nj*16 + (l & 15)] = f2bf(acc[mi][nj][rr] * inv);
            }
    } else {
        const int colb = (bj - 6)*128 + wc*64;
        #pragma unroll
        for (int mi = 0; mi < 4; ++mi)
            #pragma unroll
            for (int nj = 0; nj < 4; ++nj) {
                const int col = colb + nj*16 + (l & 15);
                const int h = col >> 6, d = col & 63;
                const int m = rbase + mi*16;        // rows m..m+3 (consecutive)
                const int b_ = m >> 8, n_ = m & 255;
                uint2 o = make_uint2(pack2bf(acc[mi][nj][0], acc[mi][nj][1]),
                                     pack2bf(acc[mi][nj][2], acc[mi][nj][3]));
                *(uint2*)&vbfT[(((size_t)b_*12 + h)*64 + d)*256 + n_] = o;
            }
    }
}

// =======================================================================
// K5: out = ctx @ w_proj^T + b_proj. (R12-exact)
// =======================================================================
__global__ __launch_bounds__(256)
void gemm_proj_mfma(const u16* __restrict__ ctxb, const u16* __restrict__ wpb,
                    const float* __restrict__ bias, float* __restrict__ out)
{
    __shared__ u16 As[128*64];
    __shared__ u16 Bs[128*64];
    const int m0 = blockIdx.x * 128;
    const int n0 = blockIdx.y * 128;
    const int tid = threadIdx.x;
    f32x4 acc[4][4];
    #pragma unroll
    for (int i = 0; i < 4; ++i)
        #pragma unroll
        for (int j = 0; j < 4; ++j) acc[i][j] = (f32x4){0.f,0.f,0.f,0.f};

    mfma_gemm_core((const char*)ctxb + (size_t)m0*1536,
                   (const char*)wpb + (size_t)n0*1536,
                   As, Bs, tid, acc);

    const int l = tid & 63, w = tid >> 6;
    const int wr = w >> 1, wc = w & 1;
    const int rbase = m0 + wr*64 + ((l >> 4) << 2);
    #pragma unroll
    for (int mi = 0; mi < 4; ++mi)
        #pragma unroll
        for (int nj = 0; nj < 4; ++nj) {
            const int col = n0 + wc*64 + nj*16 + (l & 15);
            const float bv = bias[col];
            #pragma unroll
            for (int rr = 0; rr < 4; ++rr) {
                const int m = rbase + mi*16 + rr;
                out[(size_t)m*768 + col] = acc[mi][nj][rr] + bv;
            }
        }
}

// =======================================================================
// K2: K[n][m] = exp(10*cos(n,m) - 10) off-diag, 0 on diag. bf16 out.
// (R12-exact: non-swapped epilogue, manual RNE f2bf — amplifier-upstream)
// =======================================================================
__global__ __launch_bounds__(256)
void cost_kernel(const u16* __restrict__ qnbf, u16* __restrict__ Kmat)
{
    __shared__ u16 Qa[128*64];     // [row][64 k] bf16, slot s holds global slot s^(row&7)
    __shared__ u16 Qb[128*64];
    const int bh = blockIdx.y;
    const int tr = (blockIdx.x >> 1) * 128;
    const int tc = (blockIdx.x & 1) * 128;
    const char* qb = (const char*)(qnbf + (size_t)bh * 16384);
    const int tid = threadIdx.x;
    const int l = tid & 63, w = tid >> 6;
    const int wr = w >> 1, wc = w & 1;

    {
        const int co = ((l & 7) ^ (l >> 3)) << 4;   // inverse-swizzled source slot
        const int rl = l >> 3;
        #pragma unroll
        for (int i = 0; i < 4; ++i) {
            const int ch = i*4 + w;                 // chunk 0..15
            gload_lds16(qb + (size_t)(tr + ch*8 + rl)*128 + co, (char*)Qa + ch*1024);
            gload_lds16(qb + (size_t)(tc + ch*8 + rl)*128 + co, (char*)Qb + ch*1024);
        }
    }
    __syncthreads();

    f32x4 acc[4][4];
    #pragma unroll
    for (int i = 0; i < 4; ++i)
        #pragma unroll
        for (int j = 0; j < 4; ++j) acc[i][j] = (f32x4){0.f,0.f,0.f,0.f};

    bf16x8 af[2][4], bfr[2][4];
    #pragma unroll
    for (int kk = 0; kk < 2; ++kk) {
        const int kb = kk*64 + ((l >> 4) << 4);
        #pragma unroll
        for (int f = 0; f < 4; ++f) {
            const int ra = wr*64 + f*16 + (l & 15);
            af[kk][f]  = *(const bf16x8*)((char*)Qa + ra*128 + (kb ^ ((ra & 7) << 4)));
            const int rb = wc*64 + f*16 + (l & 15);
            bfr[kk][f] = *(const bf16x8*)((char*)Qb + rb*128 + (kb ^ ((rb & 7) << 4)));
        }
    }
    #pragma unroll
    for (int mi = 0; mi < 4; ++mi)
        #pragma unroll
        for (int nj = 0; nj < 4; ++nj) {
            acc[mi][nj] = __builtin_amdgcn_mfma_f32_16x16x32_bf16(
                              af[0][mi], bfr[0][nj], acc[mi][nj], 0, 0, 0);
            acc[mi][nj] = __builtin_amdgcn_mfma_f32_16x16x32_bf16(
                              af[1][mi], bfr[1][nj], acc[mi][nj], 0, 0, 0);
        }

    u16* Kb = Kmat + (size_t)bh * 65536;
    #pragma unroll
    for (int mi = 0; mi < 4; ++mi)
        #pragma unroll
        for (int nj = 0; nj < 4; ++nj) {
            const int gr0 = tr + wr*64 + mi*16 + ((l >> 4) << 2);
            const int gc  = tc + wc*64 + nj*16 + (l & 15);
            #pragma unroll
            for (int rr = 0; rr < 4; ++rr) {
                const int gr = gr0 + rr;
                const float s = acc[mi][nj][rr];
                const float km = (gr == gc) ? 0.f : __expf(fmaf(10.f, s, -10.f));
                Kb[(size_t)gr * 256 + gc] = f2bf(km);
            }
        }
}

// =======================================================================
// K3 (split A): Sinkhorn iterations + Tmax only. (R12-exact)
// =======================================================================
__global__ __launch_bounds__(512, 2)
void sinkhorn_kernel(const u16* __restrict__ Kmat, float* __restrict__ ubuf,
                     float* __restrict__ vbuf, float* __restrict__ tmaxbuf)
{
    __shared__ __align__(16) float xv[256];
    __shared__ __align__(16) float usave[256];
    __shared__ __align__(16) u16   xbf[256];
    __shared__ float pmax[8];
    const int bh  = blockIdx.x;
    const int tid = threadIdx.x;
    const int l = tid & 63, w = tid >> 6;
    const int rowb = w * 32;
    const char* Kg = (const char*)(Kmat + (size_t)bh * 65536);

    bf16x8 kf[2][8];
    {
        const char* kb0 = Kg + (size_t)(rowb + (l & 15)) * 512 + ((l >> 4) << 4);
        #pragma unroll
        for (int t = 0; t < 2; ++t)
            #pragma unroll
            for (int ks = 0; ks < 8; ++ks)
                kf[t][ks] = *(const bf16x8*)(kb0 + t*8192 + ks*64);
    }
    if (tid < 256) xbf[tid] = 0x3f80;    // bf16(1.0)
    __syncthreads();

    for (int it = 0; it < 20; ++it) {
        f32x4 a0a = {0.f,0.f,0.f,0.f}, a0b = {0.f,0.f,0.f,0.f};
        f32x4 a1a = {0.f,0.f,0.f,0.f}, a1b = {0.f,0.f,0.f,0.f};
        #pragma unroll
        for (int ks = 0; ks < 4; ++ks) {
            const bf16x8 xf = *(const bf16x8*)((const char*)xbf + ks*64 + ((l >> 4) << 4));
            a0a = __builtin_amdgcn_mfma_f32_16x16x32_bf16(kf[0][ks], xf, a0a, 0, 0, 0);
            a1a = __builtin_amdgcn_mfma_f32_16x16x32_bf16(kf[1][ks], xf, a1a, 0, 0, 0);
        }
        #pragma unroll
        for (int ks = 4; ks < 8; ++ks) {
            const bf16x8 xf = *(const bf16x8*)((const char*)xbf + ks*64 + ((l >> 4) << 4));
            a0b = __builtin_amdgcn_mfma_f32_16x16x32_bf16(kf[0][ks], xf, a0b, 0, 0, 0);
            a1b = __builtin_amdgcn_mfma_f32_16x16x32_bf16(kf[1][ks], xf, a1b, 0, 0, 0);
        }
        float xn0[4], xn1[4];
        #pragma unroll
        for (int j = 0; j < 4; ++j) {
            xn0[j] = 0.00390625f * __builtin_amdgcn_rcpf(a0a[j] + a0b[j]);
            xn1[j] = 0.00390625f * __builtin_amdgcn_rcpf(a1a[j] + a1b[j]);
        }
        const u32 xp0 = cvtpk2bf(xn0[0], xn0[1]);
        const u32 xp1 = cvtpk2bf(xn0[2], xn0[3]);
        const u32 xp2 = cvtpk2bf(xn1[0], xn1[1]);
        const u32 xp3 = cvtpk2bf(xn1[2], xn1[3]);
        if ((l & 15) == 0) {
            const int r0 = rowb + ((l >> 4) << 2);
            *(uint2*)&xbf[r0]      = make_uint2(xp0, xp1);
            *(uint2*)&xbf[r0 + 16] = make_uint2(xp2, xp3);
            if (it == 18) {
                *(float4*)&usave[r0]      = make_float4(xn0[0], xn0[1], xn0[2], xn0[3]);
                *(float4*)&usave[r0 + 16] = make_float4(xn1[0], xn1[1], xn1[2], xn1[3]);
            }
            if (it == 19) {
                *(float4*)&xv[r0]      = make_float4(xn0[0], xn0[1], xn0[2], xn0[3]);
                *(float4*)&xv[r0 + 16] = make_float4(xn1[0], xn1[1], xn1[2], xn1[3]);
            }
        }
        __syncthreads();
    }

    {
        float mx0 = 0.f, mx1 = 0.f;
        #pragma unroll
        for (int ks = 0; ks < 8; ++ks) {
            const int mbase = ks*32 + ((l >> 4) << 3);
            const float4 va  = *(const float4*)&xv[mbase];
            const float4 vb4 = *(const float4*)&xv[mbase + 4];
            const float vv[8] = {va.x, va.y, va.z, va.w, vb4.x, vb4.y, vb4.z, vb4.w};
            #pragma unroll
            for (int j = 0; j < 8; ++j) {
                mx0 = fmaxf(mx0, bf2f((u16)kf[0][ks][j]) * vv[j]);
                mx1 = fmaxf(mx1, bf2f((u16)kf[1][ks][j]) * vv[j]);
            }
        }
        float mx = fmaxf(usave[rowb + (l & 15)] * mx0,
                         usave[rowb + 16 + (l & 15)] * mx1);
        #pragma unroll
        for (int off = 32; off > 0; off >>= 1) mx = fmaxf(mx, __shfl_xor(mx, off));
        if (l == 0) pmax[w] = mx;
    }
    __syncthreads();
    if (tid < 256) {
        ubuf[bh * 256 + tid] = usave[tid];
        vbuf[bh * 256 + tid] = xv[tid];
    }
    if (tid == 0) {
        float tm = pmax[0];
        #pragma unroll
        for (int i = 1; i < 8; ++i) tm = fmaxf(tm, pmax[i]);
        tmaxbuf[bh] = tm;
    }
}

// =======================================================================
// K4 (split B): P + PV. (R12-exact)
// =======================================================================
__global__ __launch_bounds__(512, 2)
void pv_kernel(const u16* __restrict__ Kmat, const u16* __restrict__ vbfT,
               const float* __restrict__ ubuf, const float* __restrict__ vbuf,
               const float* __restrict__ tmaxbuf, u16* __restrict__ ctxc)
{
    __shared__ u16 Vt[64*256];       // 32 KB, slot s of row d holds global slot s^(d&7)
    __shared__ __align__(16) float xv[256];
    const int bh  = blockIdx.x;
    const int b_ = bh / 12, h_ = bh - b_*12;
    const int tid = threadIdx.x;
    const int l = tid & 63, w = tid >> 6;
    const int rowb = w * 32;
    const char* Kg = (const char*)(Kmat + (size_t)bh * 65536);

    {
        const char* src = (const char*)(vbfT + (size_t)bh * 16384);
        char* dst = (char*)Vt;
        const int s = l & 31;
        #pragma unroll
        for (int i = 0; i < 4; ++i) {
            const int d = i*16 + w*2 + (l >> 5);
            gload_lds16(src + d*512 + ((s ^ (d & 7)) << 4), dst + i*8192 + w*1024);
        }
    }
    if (tid < 256) xv[tid] = vbuf[bh*256 + tid];

    bf16x8 kf[2][8];
    {
        const char* kb0 = Kg + (size_t)(rowb + (l & 15)) * 512 + ((l >> 4) << 4);
        #pragma unroll
        for (int t = 0; t < 2; ++t)
            #pragma unroll
            for (int ks = 0; ks < 8; ++ks)
                kf[t][ks] = *(const bf16x8*)(kb0 + t*8192 + ks*64);
    }
    const float itmax = 1.0f / tmaxbuf[bh];
    const float u0 = ubuf[bh*256 + rowb + (l & 15)];
    const float u1 = ubuf[bh*256 + rowb + 16 + (l & 15)];
    __syncthreads();                 // Vt + xv resident

    u16* outp = ctxc + ((size_t)b_*256)*768 + h_*64;
    #pragma unroll
    for (int t = 0; t < 2; ++t) {
        const int rown = rowb + t*16 + (l & 15);
        const float an = (t == 0 ? u0 : u1) * itmax * 0.125f;
        float psum = 0.f;
        f32x4 acc0 = {0.f,0.f,0.f,0.f}, acc1 = {0.f,0.f,0.f,0.f};
        f32x4 acc2 = {0.f,0.f,0.f,0.f}, acc3 = {0.f,0.f,0.f,0.f};
        #pragma unroll
        for (int ks = 0; ks < 8; ++ks) {
            const int mbase = ks*32 + ((l >> 4) << 3);
            const float4 va  = *(const float4*)&xv[mbase];
            const float4 vb4 = *(const float4*)&xv[mbase + 4];
            const float vv[8] = {va.x, va.y, va.z, va.w, vb4.x, vb4.y, vb4.z, vb4.w};
            float p[8];
            #pragma unroll
            for (int j = 0; j < 8; ++j)
                p[j] = __expf(an * bf2f((u16)kf[t][ks][j]) * vv[j]);
            const int dj = rown - mbase;
            if (dj >= 0 && dj < 8) p[dj] = 1.13314845f;     // exp(0.125)
            psum += ((p[0]+p[1]) + (p[2]+p[3])) + ((p[4]+p[5]) + (p[6]+p[7]));
            uint4 pwv = make_uint4(cvtpk2bf(p[0], p[1]), cvtpk2bf(p[2], p[3]),
                                   cvtpk2bf(p[4], p[5]), cvtpk2bf(p[6], p[7]));
            const bf16x8 pf = *(const bf16x8*)&pwv;
            const int bc = ks*64 + ((l >> 4) << 4);
            {
                const int d = (l & 15);
                const bf16x8 vf = *(const bf16x8*)((char*)Vt + d*512 + (bc ^ ((d & 7) << 4)));
                acc0 = __builtin_amdgcn_mfma_f32_16x16x32_bf16(vf, pf, acc0, 0, 0, 0);
            }
            {
                const int d = 16 + (l & 15);
                const bf16x8 vf = *(const bf16x8*)((char*)Vt + d*512 + (bc ^ ((d & 7) << 4)));
                acc1 = __builtin_amdgcn_mfma_f32_16x16x32_bf16(vf, pf, acc1, 0, 0, 0);
            }
            {
                const int d = 32 + (l & 15);
                const bf16x8 vf = *(const bf16x8*)((char*)Vt + d*512 + (bc ^ ((d & 7) << 4)));
                acc2 = __builtin_amdgcn_mfma_f32_16x16x32_bf16(vf, pf, acc2, 0, 0, 0);
            }
            {
                const int d = 48 + (l & 15);
                const bf16x8 vf = *(const bf16x8*)((char*)Vt + d*512 + (bc ^ ((d & 7) << 4)));
                acc3 = __builtin_amdgcn_mfma_f32_16x16x32_bf16(vf, pf, acc3, 0, 0, 0);
            }
        }
        psum += __shfl_xor(psum, 16);
        psum += __shfl_xor(psum, 32);                  // 4 lanes/row summed
        const float is = 1.0f / psum;
        const int d0 = (l >> 4) << 2;
        uint2 o0 = make_uint2(cvtpk2bf(acc0[0]*is, acc0[1]*is), cvtpk2bf(acc0[2]*is, acc0[3]*is));
        uint2 o1 = make_uint2(cvtpk2bf(acc1[0]*is, acc1[1]*is), cvtpk2bf(acc1[2]*is, acc1[3]*is));
        uint2 o2 = make_uint2(cvtpk2bf(acc2[0]*is, acc2[1]*is), cvtpk2bf(acc2[2]*is, acc2[3]*is));
        uint2 o3 = make_uint2(cvtpk2bf(acc3[0]*is, acc3[1]*is), cvtpk2bf(acc3[2]*is, acc3[3]*is));
        u16* orow = outp + (size_t)rown*768;
        *(uint2*)&orow[d0]      = o0;
        *(uint2*)&orow[16 + d0] = o1;
        *(uint2*)&orow[32 + d0] = o2;
        *(uint2*)&orow[48 + d0] = o3;
    }
}

// =======================================================================
extern "C" void kernel_launch(void* const* d_in, const int* in_sizes, int n_in,
                              void* d_out, int out_size, void* d_ws, size_t ws_size,
                              hipStream_t stream)
{
    (void)in_sizes; (void)n_in; (void)out_size; (void)ws_size;
    const float* x      = (const float*)d_in[0];
    const float* w_qkv  = (const float*)d_in[1];
    const float* w_proj = (const float*)d_in[2];
    const float* b_proj = (const float*)d_in[3];
    float* out = (float*)d_out;

    char* w = (char*)d_ws;
    // workspace layout (bytes):
    u16*   xbf  = (u16*)  (w);                     //  25,165,824  x bf16 [16384][768]
    u16*   wqv  = (u16*)  (w + 25165824);          //   2,359,296  w q+v rows bf16 [1536][768]
    u16*   wpb  = (u16*)  (w + 27525120);          //   1,179,648  w_proj bf16 [768][768]
    u16*   qnbf = (u16*)  (w + 28704768);          //  25,165,824  qn bf16 [768][256][64]
    u16*   vbfT = (u16*)  (w + 79036416);          //  25,165,824  v^T bf16 [768][64][256]
    u16*   ctxc = (u16*)  (w + 104202240);         //  25,165,824  ctx bf16 [64][256][768]
    float* ub   = (float*)(w + 129368064);         //     786,432  u [768][256]
    float* vb   = (float*)(w + 130154496);         //     786,432  v [768][256]
    float* tmx  = (float*)(w + 130940928);         //       3,072  tmax [768]
    u16*   Km   = (u16*)  (w + 130944000);         // 100,663,296  K bf16 [768][256][256]
    // total ~231.6 MB

    conv_all       <<<dim3(7008),    256, 0, stream>>>(x, w_qkv, w_proj, xbf, wqv, wpb);
    gemm_qkv_mfma  <<<dim3(128, 12), 256, 0, stream>>>(xbf, wqv, qnbf, vbfT);
    cost_kernel    <<<dim3(4, 768),  256, 0, stream>>>(qnbf, Km);
    sinkhorn_kernel<<<dim3(768),     512, 0, stream>>>(Km, ub, vb, tmx);
    pv_kernel      <<<dim3(768),     512, 0, stream>>>(Km, vbfT, ub, vb, tmx, ctxc);
    gemm_proj_mfma <<<dim3(128, 6),  256, 0, stream>>>(ctxc, wpb, b_proj, out);
}

// Round 16
// 210.281 us; speedup vs baseline: 1.0899x; 1.0265x over previous
//
#include <hip/hip_runtime.h>

typedef unsigned short u16;
typedef unsigned int   u32;
typedef __attribute__((ext_vector_type(8))) short bf16x8;
typedef __attribute__((ext_vector_type(4))) float f32x4;

// ---------- bf16 helpers (manual, RNE) ----------
__device__ __forceinline__ u16 f2bf(float f) {
    u32 u = __float_as_uint(f);
    u += 0x7fffu + ((u >> 16) & 1u);
    return (u16)(u >> 16);
}
__device__ __forceinline__ float bf2f(u16 s) {
    return __uint_as_float(((u32)s) << 16);
}
__device__ __forceinline__ u32 pack2bf(float f0, float f1) {
    return (u32)f2bf(f0) | ((u32)f2bf(f1) << 16);
}
// HW packed conversion (validated on P/ctx/x-iterate paths only — NOT
// upstream of the exp(10*cos-10) amplifier; see R13 post-mortem)
__device__ __forceinline__ u32 cvtpk2bf(float f0, float f1) {
    u32 r;
    asm("v_cvt_pk_bf16_f32 %0, %1, %2" : "=v"(r) : "v"(f0), "v"(f1));
    return r;
}

__device__ __forceinline__ void gload_lds16(const void* g, void* l) {
    __builtin_amdgcn_global_load_lds(
        (const __attribute__((address_space(1))) u32*)g,
        (__attribute__((address_space(3))) u32*)l, 16, 0, 0);
}

// =======================================================================
// Fused fp32 -> bf16 conversion for ALL three inputs (one launch).
// =======================================================================
__global__ __launch_bounds__(256)
void conv_all(const float* __restrict__ x, const float* __restrict__ wqkv,
              const float* __restrict__ wproj, u16* __restrict__ xbf,
              u16* __restrict__ wqv, u16* __restrict__ wpb)
{
    const int i = blockIdx.x * 256 + threadIdx.x;
    if (i < 1572864) {
        const float4 a = ((const float4*)x)[2*i];
        const float4 b = ((const float4*)x)[2*i + 1];
        ((uint4*)xbf)[i] = make_uint4(pack2bf(a.x,a.y), pack2bf(a.z,a.w),
                                      pack2bf(b.x,b.y), pack2bf(b.z,b.w));
    } else if (i < 1572864 + 147456) {
        const int j = i - 1572864;
        const int row = j / 96;
        const int cc  = (j - row * 96) * 8;
        const int srow = row + (row >= 768 ? 768 : 0);
        const float4 a = *(const float4*)&wqkv[(size_t)srow*768 + cc];
        const float4 b = *(const float4*)&wqkv[(size_t)srow*768 + cc + 4];
        *(uint4*)&wqv[(size_t)row*768 + cc] =
            make_uint4(pack2bf(a.x,a.y), pack2bf(a.z,a.w),
                       pack2bf(b.x,b.y), pack2bf(b.z,b.w));
    } else if (i < 1572864 + 147456 + 73728) {
        const int j = i - 1572864 - 147456;
        const float4 a = ((const float4*)wproj)[2*j];
        const float4 b = ((const float4*)wproj)[2*j + 1];
        ((uint4*)wpb)[j] = make_uint4(pack2bf(a.x,a.y), pack2bf(a.z,a.w),
                                      pack2bf(b.x,b.y), pack2bf(b.z,b.w));
    }
}

// =======================================================================
// Shared MFMA GEMM core (used by proj): C[128x128] tile, K=768.
// =======================================================================
__device__ __forceinline__ void mfma_gemm_core(
    const char* __restrict__ Arow0,   // &A[m0][0] as bytes (row stride 1536)
    const char* __restrict__ Brow0,   // &B[n0][0] as bytes
    u16* As, u16* Bs, const int tid, f32x4 acc[4][4])
{
    const int l  = tid & 63, w = tid >> 6;
    const int wr = w >> 1,  wc = w & 1;
    char* Asb = (char*)As;
    char* Bsb = (char*)Bs;
    const int co = 16 * ((l & 7) ^ (l >> 3));       // swizzled global byte col
    const size_t rstep = (size_t)(l >> 3) * 1536;
    const int rsw = (l & 7) << 4;                   // read-side XOR

    for (int k0 = 0; k0 < 1536; k0 += 128) {        // 12 K-steps of 64 bf16
        #pragma unroll
        for (int i = 0; i < 4; ++i) {
            const int rb = i*32 + w*8;
            gload_lds16(Arow0 + (size_t)rb*1536 + rstep + k0 + co, Asb + i*4096 + w*1024);
            gload_lds16(Brow0 + (size_t)rb*1536 + rstep + k0 + co, Bsb + i*4096 + w*1024);
        }
        __syncthreads();
        bf16x8 af[2][4], bfr[2][4];
        #pragma unroll
        for (int kk = 0; kk < 2; ++kk) {
            const int coff = (kk*64 + ((l >> 4) << 4)) ^ rsw;
            #pragma unroll
            for (int mi = 0; mi < 4; ++mi) {
                const int rowA = wr*64 + mi*16 + (l & 15);
                af[kk][mi]  = *(const bf16x8*)(Asb + rowA*128 + coff);
                const int rowB = wc*64 + mi*16 + (l & 15);
                bfr[kk][mi] = *(const bf16x8*)(Bsb + rowB*128 + coff);
            }
        }
        #pragma unroll
        for (int mi = 0; mi < 4; ++mi)
            #pragma unroll
            for (int nj = 0; nj < 4; ++nj) {
                acc[mi][nj] = __builtin_amdgcn_mfma_f32_16x16x32_bf16(
                                  af[0][mi], bfr[0][nj], acc[mi][nj], 0, 0, 0);
                acc[mi][nj] = __builtin_amdgcn_mfma_f32_16x16x32_bf16(
                                  af[1][mi], bfr[1][nj], acc[mi][nj], 0, 0, 0);
            }
        __syncthreads();
    }
}

// =======================================================================
// K0 (widened tile): q+v projection + FUSED q-normalize, ONE block per
// (m0, bj in 0..5) computes the 128x128 q-block AND the 128x128 v-block.
// A-tile staged ONCE per K-step; two B-panels (q-cols, v-cols); 64 MFMAs
// per K-step against the same 2 barriers -> per-FLOP stage/barrier cost
// halves vs R15. Epilogues identical to R15's validated q/v branches.
// =======================================================================
__global__ __launch_bounds__(256, 2)
void gemm_qkv_mfma(const u16* __restrict__ xbf, const u16* __restrict__ wqv,
                   u16* __restrict__ qnbf, u16* __restrict__ vbfT)
{
    __shared__ u16 As[128*64];     // 16 KB  A panel (x rows)
    __shared__ u16 Bq[128*64];     // 16 KB  q-col panel (wqv rows bj*128..)
    __shared__ u16 Bv[128*64];     // 16 KB  v-col panel (wqv rows 768+bj*128..)
    const int m0 = blockIdx.x * 128;
    const int bj = blockIdx.y;                      // 0..5
    const int tid = threadIdx.x;
    const int l = tid & 63, w = tid >> 6;
    const int wr = w >> 1, wc = w & 1;

    f32x4 accq[4][4], accv[4][4];
    #pragma unroll
    for (int i = 0; i < 4; ++i)
        #pragma unroll
        for (int j = 0; j < 4; ++j) {
            accq[i][j] = (f32x4){0.f,0.f,0.f,0.f};
            accv[i][j] = (f32x4){0.f,0.f,0.f,0.f};
        }

    const char* Ar  = (const char*)xbf + (size_t)m0*1536;
    const char* Bqr = (const char*)wqv + (size_t)(bj*128)*1536;
    const char* Bvr = (const char*)wqv + (size_t)(768 + bj*128)*1536;
    char* Asb = (char*)As;
    char* Bqb = (char*)Bq;
    char* Bvb = (char*)Bv;
    const int co = 16 * ((l & 7) ^ (l >> 3));       // swizzled global byte col
    const size_t rstep = (size_t)(l >> 3) * 1536;
    const int rsw = (l & 7) << 4;                   // read-side XOR

    for (int k0 = 0; k0 < 1536; k0 += 128) {        // 12 K-steps of 64 bf16
        #pragma unroll
        for (int i = 0; i < 4; ++i) {
            const int rb = i*32 + w*8;
            const size_t goff = (size_t)rb*1536 + rstep + k0 + co;
            gload_lds16(Ar  + goff, Asb + i*4096 + w*1024);
            gload_lds16(Bqr + goff, Bqb + i*4096 + w*1024);
            gload_lds16(Bvr + goff, Bvb + i*4096 + w*1024);
        }
        __syncthreads();
        #pragma unroll
        for (int kk = 0; kk < 2; ++kk) {
            const int coff = (kk*64 + ((l >> 4) << 4)) ^ rsw;
            bf16x8 af[4], bq[4], bv[4];
            #pragma unroll
            for (int mi = 0; mi < 4; ++mi) {
                const int rowA = wr*64 + mi*16 + (l & 15);
                af[mi] = *(const bf16x8*)(Asb + rowA*128 + coff);
                const int rowB = wc*64 + mi*16 + (l & 15);
                bq[mi] = *(const bf16x8*)(Bqb + rowB*128 + coff);
                bv[mi] = *(const bf16x8*)(Bvb + rowB*128 + coff);
            }
            #pragma unroll
            for (int mi = 0; mi < 4; ++mi)
                #pragma unroll
                for (int nj = 0; nj < 4; ++nj)
                    accq[mi][nj] = __builtin_amdgcn_mfma_f32_16x16x32_bf16(
                                       af[mi], bq[nj], accq[mi][nj], 0, 0, 0);
            #pragma unroll
            for (int mi = 0; mi < 4; ++mi)
                #pragma unroll
                for (int nj = 0; nj < 4; ++nj)
                    accv[mi][nj] = __builtin_amdgcn_mfma_f32_16x16x32_bf16(
                                       af[mi], bv[nj], accv[mi][nj], 0, 0, 0);
        }
        __syncthreads();
    }

    const int rbase = m0 + wr*64 + ((l >> 4) << 2);
    // ---- q epilogue (R15-exact): fused normalize, h = 2*bj + wc
    {
        const int h = 2*bj + wc;                   // wave's 64 q-cols = head h
        #pragma unroll
        for (int mi = 0; mi < 4; ++mi)
            #pragma unroll
            for (int rr = 0; rr < 4; ++rr) {
                float s =      accq[mi][0][rr]*accq[mi][0][rr];
                s = fmaf(accq[mi][1][rr], accq[mi][1][rr], s);
                s = fmaf(accq[mi][2][rr], accq[mi][2][rr], s);
                s = fmaf(accq[mi][3][rr], accq[mi][3][rr], s);
                #pragma unroll
                for (int off = 1; off < 16; off <<= 1) s += __shfl_xor(s, off);
                const float inv = 1.0f / (sqrtf(s) + 1e-8f);
                const int m = rbase + mi*16 + rr;
                const int b_ = m >> 8, n_ = m & 255;
                u16* row = qnbf + ((((size_t)b_*12 + h) << 8) + n_)*64;
                #pragma unroll
                for (int nj = 0; nj < 4; ++nj)
                    row[nj*16 + (l & 15)] = f2bf(accq[mi][nj][rr] * inv);
            }
    }
    // ---- v epilogue (R15-exact): transposed bf16 store, colb = bj*128+wc*64
    {
        const int colb = bj*128 + wc*64;
        #pragma unroll
        for (int mi = 0; mi < 4; ++mi)
            #pragma unroll
            for (int nj = 0; nj < 4; ++nj) {
                const int col = colb + nj*16 + (l & 15);
                const int h = col >> 6, d = col & 63;
                const int m = rbase + mi*16;        // rows m..m+3 (consecutive)
                const int b_ = m >> 8, n_ = m & 255;
                uint2 o = make_uint2(pack2bf(accv[mi][nj][0], accv[mi][nj][1]),
                                     pack2bf(accv[mi][nj][2], accv[mi][nj][3]));
                *(uint2*)&vbfT[(((size_t)b_*12 + h)*64 + d)*256 + n_] = o;
            }
    }
}

// =======================================================================
// K5: out = ctx @ w_proj^T + b_proj. (R15-exact)
// =======================================================================
__global__ __launch_bounds__(256)
void gemm_proj_mfma(const u16* __restrict__ ctxb, const u16* __restrict__ wpb,
                    const float* __restrict__ bias, float* __restrict__ out)
{
    __shared__ u16 As[128*64];
    __shared__ u16 Bs[128*64];
    const int m0 = blockIdx.x * 128;
    const int n0 = blockIdx.y * 128;
    const int tid = threadIdx.x;
    f32x4 acc[4][4];
    #pragma unroll
    for (int i = 0; i < 4; ++i)
        #pragma unroll
        for (int j = 0; j < 4; ++j) acc[i][j] = (f32x4){0.f,0.f,0.f,0.f};

    mfma_gemm_core((const char*)ctxb + (size_t)m0*1536,
                   (const char*)wpb + (size_t)n0*1536,
                   As, Bs, tid, acc);

    const int l = tid & 63, w = tid >> 6;
    const int wr = w >> 1, wc = w & 1;
    const int rbase = m0 + wr*64 + ((l >> 4) << 2);
    #pragma unroll
    for (int mi = 0; mi < 4; ++mi)
        #pragma unroll
        for (int nj = 0; nj < 4; ++nj) {
            const int col = n0 + wc*64 + nj*16 + (l & 15);
            const float bv = bias[col];
            #pragma unroll
            for (int rr = 0; rr < 4; ++rr) {
                const int m = rbase + mi*16 + rr;
                out[(size_t)m*768 + col] = acc[mi][nj][rr] + bv;
            }
        }
}

// =======================================================================
// K2: K[n][m] = exp(10*cos(n,m) - 10) off-diag, 0 on diag. (R15-exact)
// =======================================================================
__global__ __launch_bounds__(256)
void cost_kernel(const u16* __restrict__ qnbf, u16* __restrict__ Kmat)
{
    __shared__ u16 Qa[128*64];     // [row][64 k] bf16, slot s holds global slot s^(row&7)
    __shared__ u16 Qb[128*64];
    const int bh = blockIdx.y;
    const int tr = (blockIdx.x >> 1) * 128;
    const int tc = (blockIdx.x & 1) * 128;
    const char* qb = (const char*)(qnbf + (size_t)bh * 16384);
    const int tid = threadIdx.x;
    const int l = tid & 63, w = tid >> 6;
    const int wr = w >> 1, wc = w & 1;

    {
        const int co = ((l & 7) ^ (l >> 3)) << 4;   // inverse-swizzled source slot
        const int rl = l >> 3;
        #pragma unroll
        for (int i = 0; i < 4; ++i) {
            const int ch = i*4 + w;                 // chunk 0..15
            gload_lds16(qb + (size_t)(tr + ch*8 + rl)*128 + co, (char*)Qa + ch*1024);
            gload_lds16(qb + (size_t)(tc + ch*8 + rl)*128 + co, (char*)Qb + ch*1024);
        }
    }
    __syncthreads();

    f32x4 acc[4][4];
    #pragma unroll
    for (int i = 0; i < 4; ++i)
        #pragma unroll
        for (int j = 0; j < 4; ++j) acc[i][j] = (f32x4){0.f,0.f,0.f,0.f};

    bf16x8 af[2][4], bfr[2][4];
    #pragma unroll
    for (int kk = 0; kk < 2; ++kk) {
        const int kb = kk*64 + ((l >> 4) << 4);
        #pragma unroll
        for (int f = 0; f < 4; ++f) {
            const int ra = wr*64 + f*16 + (l & 15);
            af[kk][f]  = *(const bf16x8*)((char*)Qa + ra*128 + (kb ^ ((ra & 7) << 4)));
            const int rb = wc*64 + f*16 + (l & 15);
            bfr[kk][f] = *(const bf16x8*)((char*)Qb + rb*128 + (kb ^ ((rb & 7) << 4)));
        }
    }
    #pragma unroll
    for (int mi = 0; mi < 4; ++mi)
        #pragma unroll
        for (int nj = 0; nj < 4; ++nj) {
            acc[mi][nj] = __builtin_amdgcn_mfma_f32_16x16x32_bf16(
                              af[0][mi], bfr[0][nj], acc[mi][nj], 0, 0, 0);
            acc[mi][nj] = __builtin_amdgcn_mfma_f32_16x16x32_bf16(
                              af[1][mi], bfr[1][nj], acc[mi][nj], 0, 0, 0);
        }

    u16* Kb = Kmat + (size_t)bh * 65536;
    #pragma unroll
    for (int mi = 0; mi < 4; ++mi)
        #pragma unroll
        for (int nj = 0; nj < 4; ++nj) {
            const int gr0 = tr + wr*64 + mi*16 + ((l >> 4) << 2);
            const int gc  = tc + wc*64 + nj*16 + (l & 15);
            #pragma unroll
            for (int rr = 0; rr < 4; ++rr) {
                const int gr = gr0 + rr;
                const float s = acc[mi][nj][rr];
                const float km = (gr == gc) ? 0.f : __expf(fmaf(10.f, s, -10.f));
                Kb[(size_t)gr * 256 + gc] = f2bf(km);
            }
        }
}

// =======================================================================
// K3 (split A): Sinkhorn iterations + Tmax only. (R15-exact)
// =======================================================================
__global__ __launch_bounds__(512, 2)
void sinkhorn_kernel(const u16* __restrict__ Kmat, float* __restrict__ ubuf,
                     float* __restrict__ vbuf, float* __restrict__ tmaxbuf)
{
    __shared__ __align__(16) float xv[256];
    __shared__ __align__(16) float usave[256];
    __shared__ __align__(16) u16   xbf[256];
    __shared__ float pmax[8];
    const int bh  = blockIdx.x;
    const int tid = threadIdx.x;
    const int l = tid & 63, w = tid >> 6;
    const int rowb = w * 32;
    const char* Kg = (const char*)(Kmat + (size_t)bh * 65536);

    bf16x8 kf[2][8];
    {
        const char* kb0 = Kg + (size_t)(rowb + (l & 15)) * 512 + ((l >> 4) << 4);
        #pragma unroll
        for (int t = 0; t < 2; ++t)
            #pragma unroll
            for (int ks = 0; ks < 8; ++ks)
                kf[t][ks] = *(const bf16x8*)(kb0 + t*8192 + ks*64);
    }
    if (tid < 256) xbf[tid] = 0x3f80;    // bf16(1.0)
    __syncthreads();

    for (int it = 0; it < 20; ++it) {
        f32x4 a0a = {0.f,0.f,0.f,0.f}, a0b = {0.f,0.f,0.f,0.f};
        f32x4 a1a = {0.f,0.f,0.f,0.f}, a1b = {0.f,0.f,0.f,0.f};
        #pragma unroll
        for (int ks = 0; ks < 4; ++ks) {
            const bf16x8 xf = *(const bf16x8*)((const char*)xbf + ks*64 + ((l >> 4) << 4));
            a0a = __builtin_amdgcn_mfma_f32_16x16x32_bf16(kf[0][ks], xf, a0a, 0, 0, 0);
            a1a = __builtin_amdgcn_mfma_f32_16x16x32_bf16(kf[1][ks], xf, a1a, 0, 0, 0);
        }
        #pragma unroll
        for (int ks = 4; ks < 8; ++ks) {
            const bf16x8 xf = *(const bf16x8*)((const char*)xbf + ks*64 + ((l >> 4) << 4));
            a0b = __builtin_amdgcn_mfma_f32_16x16x32_bf16(kf[0][ks], xf, a0b, 0, 0, 0);
            a1b = __builtin_amdgcn_mfma_f32_16x16x32_bf16(kf[1][ks], xf, a1b, 0, 0, 0);
        }
        float xn0[4], xn1[4];
        #pragma unroll
        for (int j = 0; j < 4; ++j) {
            xn0[j] = 0.00390625f * __builtin_amdgcn_rcpf(a0a[j] + a0b[j]);
            xn1[j] = 0.00390625f * __builtin_amdgcn_rcpf(a1a[j] + a1b[j]);
        }
        const u32 xp0 = cvtpk2bf(xn0[0], xn0[1]);
        const u32 xp1 = cvtpk2bf(xn0[2], xn0[3]);
        const u32 xp2 = cvtpk2bf(xn1[0], xn1[1]);
        const u32 xp3 = cvtpk2bf(xn1[2], xn1[3]);
        if ((l & 15) == 0) {
            const int r0 = rowb + ((l >> 4) << 2);
            *(uint2*)&xbf[r0]      = make_uint2(xp0, xp1);
            *(uint2*)&xbf[r0 + 16] = make_uint2(xp2, xp3);
            if (it == 18) {
                *(float4*)&usave[r0]      = make_float4(xn0[0], xn0[1], xn0[2], xn0[3]);
                *(float4*)&usave[r0 + 16] = make_float4(xn1[0], xn1[1], xn1[2], xn1[3]);
            }
            if (it == 19) {
                *(float4*)&xv[r0]      = make_float4(xn0[0], xn0[1], xn0[2], xn0[3]);
                *(float4*)&xv[r0 + 16] = make_float4(xn1[0], xn1[1], xn1[2], xn1[3]);
            }
        }
        __syncthreads();
    }

    {
        float mx0 = 0.f, mx1 = 0.f;
        #pragma unroll
        for (int ks = 0; ks < 8; ++ks) {
            const int mbase = ks*32 + ((l >> 4) << 3);
            const float4 va  = *(const float4*)&xv[mbase];
            const float4 vb4 = *(const float4*)&xv[mbase + 4];
            const float vv[8] = {va.x, va.y, va.z, va.w, vb4.x, vb4.y, vb4.z, vb4.w};
            #pragma unroll
            for (int j = 0; j < 8; ++j) {
                mx0 = fmaxf(mx0, bf2f((u16)kf[0][ks][j]) * vv[j]);
                mx1 = fmaxf(mx1, bf2f((u16)kf[1][ks][j]) * vv[j]);
            }
        }
        float mx = fmaxf(usave[rowb + (l & 15)] * mx0,
                         usave[rowb + 16 + (l & 15)] * mx1);
        #pragma unroll
        for (int off = 32; off > 0; off >>= 1) mx = fmaxf(mx, __shfl_xor(mx, off));
        if (l == 0) pmax[w] = mx;
    }
    __syncthreads();
    if (tid < 256) {
        ubuf[bh * 256 + tid] = usave[tid];
        vbuf[bh * 256 + tid] = xv[tid];
    }
    if (tid == 0) {
        float tm = pmax[0];
        #pragma unroll
        for (int i = 1; i < 8; ++i) tm = fmaxf(tm, pmax[i]);
        tmaxbuf[bh] = tm;
    }
}

// =======================================================================
// K4 (split B): P + PV. (R15-exact)
// =======================================================================
__global__ __launch_bounds__(512, 2)
void pv_kernel(const u16* __restrict__ Kmat, const u16* __restrict__ vbfT,
               const float* __restrict__ ubuf, const float* __restrict__ vbuf,
               const float* __restrict__ tmaxbuf, u16* __restrict__ ctxc)
{
    __shared__ u16 Vt[64*256];       // 32 KB, slot s of row d holds global slot s^(d&7)
    __shared__ __align__(16) float xv[256];
    const int bh  = blockIdx.x;
    const int b_ = bh / 12, h_ = bh - b_*12;
    const int tid = threadIdx.x;
    const int l = tid & 63, w = tid >> 6;
    const int rowb = w * 32;
    const char* Kg = (const char*)(Kmat + (size_t)bh * 65536);

    {
        const char* src = (const char*)(vbfT + (size_t)bh * 16384);
        char* dst = (char*)Vt;
        const int s = l & 31;
        #pragma unroll
        for (int i = 0; i < 4; ++i) {
            const int d = i*16 + w*2 + (l >> 5);
            gload_lds16(src + d*512 + ((s ^ (d & 7)) << 4), dst + i*8192 + w*1024);
        }
    }
    if (tid < 256) xv[tid] = vbuf[bh*256 + tid];

    bf16x8 kf[2][8];
    {
        const char* kb0 = Kg + (size_t)(rowb + (l & 15)) * 512 + ((l >> 4) << 4);
        #pragma unroll
        for (int t = 0; t < 2; ++t)
            #pragma unroll
            for (int ks = 0; ks < 8; ++ks)
                kf[t][ks] = *(const bf16x8*)(kb0 + t*8192 + ks*64);
    }
    const float itmax = 1.0f / tmaxbuf[bh];
    const float u0 = ubuf[bh*256 + rowb + (l & 15)];
    const float u1 = ubuf[bh*256 + rowb + 16 + (l & 15)];
    __syncthreads();                 // Vt + xv resident

    u16* outp = ctxc + ((size_t)b_*256)*768 + h_*64;
    #pragma unroll
    for (int t = 0; t < 2; ++t) {
        const int rown = rowb + t*16 + (l & 15);
        const float an = (t == 0 ? u0 : u1) * itmax * 0.125f;
        float psum = 0.f;
        f32x4 acc0 = {0.f,0.f,0.f,0.f}, acc1 = {0.f,0.f,0.f,0.f};
        f32x4 acc2 = {0.f,0.f,0.f,0.f}, acc3 = {0.f,0.f,0.f,0.f};
        #pragma unroll
        for (int ks = 0; ks < 8; ++ks) {
            const int mbase = ks*32 + ((l >> 4) << 3);
            const float4 va  = *(const float4*)&xv[mbase];
            const float4 vb4 = *(const float4*)&xv[mbase + 4];
            const float vv[8] = {va.x, va.y, va.z, va.w, vb4.x, vb4.y, vb4.z, vb4.w};
            float p[8];
            #pragma unroll
            for (int j = 0; j < 8; ++j)
                p[j] = __expf(an * bf2f((u16)kf[t][ks][j]) * vv[j]);
            const int dj = rown - mbase;
            if (dj >= 0 && dj < 8) p[dj] = 1.13314845f;     // exp(0.125)
            psum += ((p[0]+p[1]) + (p[2]+p[3])) + ((p[4]+p[5]) + (p[6]+p[7]));
            uint4 pwv = make_uint4(cvtpk2bf(p[0], p[1]), cvtpk2bf(p[2], p[3]),
                                   cvtpk2bf(p[4], p[5]), cvtpk2bf(p[6], p[7]));
            const bf16x8 pf = *(const bf16x8*)&pwv;
            const int bc = ks*64 + ((l >> 4) << 4);
            {
                const int d = (l & 15);
                const bf16x8 vf = *(const bf16x8*)((char*)Vt + d*512 + (bc ^ ((d & 7) << 4)));
                acc0 = __builtin_amdgcn_mfma_f32_16x16x32_bf16(vf, pf, acc0, 0, 0, 0);
            }
            {
                const int d = 16 + (l & 15);
                const bf16x8 vf = *(const bf16x8*)((char*)Vt + d*512 + (bc ^ ((d & 7) << 4)));
                acc1 = __builtin_amdgcn_mfma_f32_16x16x32_bf16(vf, pf, acc1, 0, 0, 0);
            }
            {
                const int d = 32 + (l & 15);
                const bf16x8 vf = *(const bf16x8*)((char*)Vt + d*512 + (bc ^ ((d & 7) << 4)));
                acc2 = __builtin_amdgcn_mfma_f32_16x16x32_bf16(vf, pf, acc2, 0, 0, 0);
            }
            {
                const int d = 48 + (l & 15);
                const bf16x8 vf = *(const bf16x8*)((char*)Vt + d*512 + (bc ^ ((d & 7) << 4)));
                acc3 = __builtin_amdgcn_mfma_f32_16x16x32_bf16(vf, pf, acc3, 0, 0, 0);
            }
        }
        psum += __shfl_xor(psum, 16);
        psum += __shfl_xor(psum, 32);                  // 4 lanes/row summed
        const float is = 1.0f / psum;
        const int d0 = (l >> 4) << 2;
        uint2 o0 = make_uint2(cvtpk2bf(acc0[0]*is, acc0[1]*is), cvtpk2bf(acc0[2]*is, acc0[3]*is));
        uint2 o1 = make_uint2(cvtpk2bf(acc1[0]*is, acc1[1]*is), cvtpk2bf(acc1[2]*is, acc1[3]*is));
        uint2 o2 = make_uint2(cvtpk2bf(acc2[0]*is, acc2[1]*is), cvtpk2bf(acc2[2]*is, acc2[3]*is));
        uint2 o3 = make_uint2(cvtpk2bf(acc3[0]*is, acc3[1]*is), cvtpk2bf(acc3[2]*is, acc3[3]*is));
        u16* orow = outp + (size_t)rown*768;
        *(uint2*)&orow[d0]      = o0;
        *(uint2*)&orow[16 + d0] = o1;
        *(uint2*)&orow[32 + d0] = o2;
        *(uint2*)&orow[48 + d0] = o3;
    }
}

// =======================================================================
extern "C" void kernel_launch(void* const* d_in, const int* in_sizes, int n_in,
                              void* d_out, int out_size, void* d_ws, size_t ws_size,
                              hipStream_t stream)
{
    (void)in_sizes; (void)n_in; (void)out_size; (void)ws_size;
    const float* x      = (const float*)d_in[0];
    const float* w_qkv  = (const float*)d_in[1];
    const float* w_proj = (const float*)d_in[2];
    const float* b_proj = (const float*)d_in[3];
    float* out = (float*)d_out;

    char* w = (char*)d_ws;
    // workspace layout (bytes):
    u16*   xbf  = (u16*)  (w);                     //  25,165,824  x bf16 [16384][768]
    u16*   wqv  = (u16*)  (w + 25165824);          //   2,359,296  w q+v rows bf16 [1536][768]
    u16*   wpb  = (u16*)  (w + 27525120);          //   1,179,648  w_proj bf16 [768][768]
    u16*   qnbf = (u16*)  (w + 28704768);          //  25,165,824  qn bf16 [768][256][64]
    u16*   vbfT = (u16*)  (w + 79036416);          //  25,165,824  v^T bf16 [768][64][256]
    u16*   ctxc = (u16*)  (w + 104202240);         //  25,165,824  ctx bf16 [64][256][768]
    float* ub   = (float*)(w + 129368064);         //     786,432  u [768][256]
    float* vb   = (float*)(w + 130154496);         //     786,432  v [768][256]
    float* tmx  = (float*)(w + 130940928);         //       3,072  tmax [768]
    u16*   Km   = (u16*)  (w + 130944000);         // 100,663,296  K bf16 [768][256][256]
    // total ~231.6 MB

    conv_all       <<<dim3(7008),    256, 0, stream>>>(x, w_qkv, w_proj, xbf, wqv, wpb);
    gemm_qkv_mfma  <<<dim3(128, 6),  256, 0, stream>>>(xbf, wqv, qnbf, vbfT);
    cost_kernel    <<<dim3(4, 768),  256, 0, stream>>>(qnbf, Km);
    sinkhorn_kernel<<<dim3(768),     512, 0, stream>>>(Km, ub, vb, tmx);
    pv_kernel      <<<dim3(768),     512, 0, stream>>>(Km, vbfT, ub, vb, tmx, ctxc);
    gemm_proj_mfma <<<dim3(128, 6),  256, 0, stream>>>(ctxc, wpb, b_proj, out);
}

// Round 17
// 202.878 us; speedup vs baseline: 1.1296x; 1.0365x over previous
//
#include <hip/hip_runtime.h>

typedef unsigned short u16;
typedef unsigned int   u32;
typedef __attribute__((ext_vector_type(8))) short bf16x8;
typedef __attribute__((ext_vector_type(4))) float f32x4;

// ---------- bf16 helpers (manual, RNE) ----------
__device__ __forceinline__ u16 f2bf(float f) {
    u32 u = __float_as_uint(f);
    u += 0x7fffu + ((u >> 16) & 1u);
    return (u16)(u >> 16);
}
__device__ __forceinline__ float bf2f(u16 s) {
    return __uint_as_float(((u32)s) << 16);
}
__device__ __forceinline__ u32 pack2bf(float f0, float f1) {
    return (u32)f2bf(f0) | ((u32)f2bf(f1) << 16);
}
// HW packed conversion (validated on P/ctx/x-iterate paths only — NOT
// upstream of the exp(10*cos-10) amplifier; see R13 post-mortem)
__device__ __forceinline__ u32 cvtpk2bf(float f0, float f1) {
    u32 r;
    asm("v_cvt_pk_bf16_f32 %0, %1, %2" : "=v"(r) : "v"(f0), "v"(f1));
    return r;
}

__device__ __forceinline__ void gload_lds16(const void* g, void* l) {
    __builtin_amdgcn_global_load_lds(
        (const __attribute__((address_space(1))) u32*)g,
        (__attribute__((address_space(3))) u32*)l, 16, 0, 0);
}

// =======================================================================
// Fused fp32 -> bf16 conversion for ALL three inputs (one launch).
// =======================================================================
__global__ __launch_bounds__(256)
void conv_all(const float* __restrict__ x, const float* __restrict__ wqkv,
              const float* __restrict__ wproj, u16* __restrict__ xbf,
              u16* __restrict__ wqv, u16* __restrict__ wpb)
{
    const int i = blockIdx.x * 256 + threadIdx.x;
    if (i < 1572864) {
        const float4 a = ((const float4*)x)[2*i];
        const float4 b = ((const float4*)x)[2*i + 1];
        ((uint4*)xbf)[i] = make_uint4(pack2bf(a.x,a.y), pack2bf(a.z,a.w),
                                      pack2bf(b.x,b.y), pack2bf(b.z,b.w));
    } else if (i < 1572864 + 147456) {
        const int j = i - 1572864;
        const int row = j / 96;
        const int cc  = (j - row * 96) * 8;
        const int srow = row + (row >= 768 ? 768 : 0);
        const float4 a = *(const float4*)&wqkv[(size_t)srow*768 + cc];
        const float4 b = *(const float4*)&wqkv[(size_t)srow*768 + cc + 4];
        *(uint4*)&wqv[(size_t)row*768 + cc] =
            make_uint4(pack2bf(a.x,a.y), pack2bf(a.z,a.w),
                       pack2bf(b.x,b.y), pack2bf(b.z,b.w));
    } else if (i < 1572864 + 147456 + 73728) {
        const int j = i - 1572864 - 147456;
        const float4 a = ((const float4*)wproj)[2*j];
        const float4 b = ((const float4*)wproj)[2*j + 1];
        ((uint4*)wpb)[j] = make_uint4(pack2bf(a.x,a.y), pack2bf(a.z,a.w),
                                      pack2bf(b.x,b.y), pack2bf(b.z,b.w));
    }
}

// =======================================================================
// K0 (widened tile): q+v projection + FUSED q-normalize, ONE block per
// (m0, bj in 0..5): A-tile staged ONCE per K-step, two B-panels, 64 MFMAs
// per K-step against 2 barriers. (R16-validated)
// =======================================================================
__global__ __launch_bounds__(256, 2)
void gemm_qkv_mfma(const u16* __restrict__ xbf, const u16* __restrict__ wqv,
                   u16* __restrict__ qnbf, u16* __restrict__ vbfT)
{
    __shared__ u16 As[128*64];     // 16 KB  A panel (x rows)
    __shared__ u16 Bq[128*64];     // 16 KB  q-col panel (wqv rows bj*128..)
    __shared__ u16 Bv[128*64];     // 16 KB  v-col panel (wqv rows 768+bj*128..)
    const int m0 = blockIdx.x * 128;
    const int bj = blockIdx.y;                      // 0..5
    const int tid = threadIdx.x;
    const int l = tid & 63, w = tid >> 6;
    const int wr = w >> 1, wc = w & 1;

    f32x4 accq[4][4], accv[4][4];
    #pragma unroll
    for (int i = 0; i < 4; ++i)
        #pragma unroll
        for (int j = 0; j < 4; ++j) {
            accq[i][j] = (f32x4){0.f,0.f,0.f,0.f};
            accv[i][j] = (f32x4){0.f,0.f,0.f,0.f};
        }

    const char* Ar  = (const char*)xbf + (size_t)m0*1536;
    const char* Bqr = (const char*)wqv + (size_t)(bj*128)*1536;
    const char* Bvr = (const char*)wqv + (size_t)(768 + bj*128)*1536;
    char* Asb = (char*)As;
    char* Bqb = (char*)Bq;
    char* Bvb = (char*)Bv;
    const int co = 16 * ((l & 7) ^ (l >> 3));       // swizzled global byte col
    const size_t rstep = (size_t)(l >> 3) * 1536;
    const int rsw = (l & 7) << 4;                   // read-side XOR

    for (int k0 = 0; k0 < 1536; k0 += 128) {        // 12 K-steps of 64 bf16
        #pragma unroll
        for (int i = 0; i < 4; ++i) {
            const int rb = i*32 + w*8;
            const size_t goff = (size_t)rb*1536 + rstep + k0 + co;
            gload_lds16(Ar  + goff, Asb + i*4096 + w*1024);
            gload_lds16(Bqr + goff, Bqb + i*4096 + w*1024);
            gload_lds16(Bvr + goff, Bvb + i*4096 + w*1024);
        }
        __syncthreads();
        #pragma unroll
        for (int kk = 0; kk < 2; ++kk) {
            const int coff = (kk*64 + ((l >> 4) << 4)) ^ rsw;
            bf16x8 af[4], bq[4], bv[4];
            #pragma unroll
            for (int mi = 0; mi < 4; ++mi) {
                const int rowA = wr*64 + mi*16 + (l & 15);
                af[mi] = *(const bf16x8*)(Asb + rowA*128 + coff);
                const int rowB = wc*64 + mi*16 + (l & 15);
                bq[mi] = *(const bf16x8*)(Bqb + rowB*128 + coff);
                bv[mi] = *(const bf16x8*)(Bvb + rowB*128 + coff);
            }
            #pragma unroll
            for (int mi = 0; mi < 4; ++mi)
                #pragma unroll
                for (int nj = 0; nj < 4; ++nj)
                    accq[mi][nj] = __builtin_amdgcn_mfma_f32_16x16x32_bf16(
                                       af[mi], bq[nj], accq[mi][nj], 0, 0, 0);
            #pragma unroll
            for (int mi = 0; mi < 4; ++mi)
                #pragma unroll
                for (int nj = 0; nj < 4; ++nj)
                    accv[mi][nj] = __builtin_amdgcn_mfma_f32_16x16x32_bf16(
                                       af[mi], bv[nj], accv[mi][nj], 0, 0, 0);
        }
        __syncthreads();
    }

    const int rbase = m0 + wr*64 + ((l >> 4) << 2);
    // ---- q epilogue: fused normalize, h = 2*bj + wc
    {
        const int h = 2*bj + wc;                   // wave's 64 q-cols = head h
        #pragma unroll
        for (int mi = 0; mi < 4; ++mi)
            #pragma unroll
            for (int rr = 0; rr < 4; ++rr) {
                float s =      accq[mi][0][rr]*accq[mi][0][rr];
                s = fmaf(accq[mi][1][rr], accq[mi][1][rr], s);
                s = fmaf(accq[mi][2][rr], accq[mi][2][rr], s);
                s = fmaf(accq[mi][3][rr], accq[mi][3][rr], s);
                #pragma unroll
                for (int off = 1; off < 16; off <<= 1) s += __shfl_xor(s, off);
                const float inv = 1.0f / (sqrtf(s) + 1e-8f);
                const int m = rbase + mi*16 + rr;
                const int b_ = m >> 8, n_ = m & 255;
                u16* row = qnbf + ((((size_t)b_*12 + h) << 8) + n_)*64;
                #pragma unroll
                for (int nj = 0; nj < 4; ++nj)
                    row[nj*16 + (l & 15)] = f2bf(accq[mi][nj][rr] * inv);
            }
    }
    // ---- v epilogue: transposed bf16 store, colb = bj*128+wc*64
    {
        const int colb = bj*128 + wc*64;
        #pragma unroll
        for (int mi = 0; mi < 4; ++mi)
            #pragma unroll
            for (int nj = 0; nj < 4; ++nj) {
                const int col = colb + nj*16 + (l & 15);
                const int h = col >> 6, d = col & 63;
                const int m = rbase + mi*16;        // rows m..m+3 (consecutive)
                const int b_ = m >> 8, n_ = m & 255;
                uint2 o = make_uint2(pack2bf(accv[mi][nj][0], accv[mi][nj][1]),
                                     pack2bf(accv[mi][nj][2], accv[mi][nj][3]));
                *(uint2*)&vbfT[(((size_t)b_*12 + h)*64 + d)*256 + n_] = o;
            }
    }
}

// =======================================================================
// K5 (widened tile): out = ctx @ w_proj^T + b_proj. ONE block per
// (m0, bj in 0..2) computes TWO 128x128 n-tiles (n0 = bj*256, n0+128):
// A staged once per K-step, two B panels, 64 MFMAs / 2 barriers.
// Epilogue = R15-exact proj epilogue twice (col bases n0, n0+128).
// =======================================================================
__global__ __launch_bounds__(256, 2)
void gemm_proj_mfma(const u16* __restrict__ ctxb, const u16* __restrict__ wpb,
                    const float* __restrict__ bias, float* __restrict__ out)
{
    __shared__ u16 As[128*64];     // 16 KB  ctx rows
    __shared__ u16 B1[128*64];     // 16 KB  wpb rows n0..
    __shared__ u16 B2[128*64];     // 16 KB  wpb rows n0+128..
    const int m0 = blockIdx.x * 128;
    const int n0 = blockIdx.y * 256;
    const int tid = threadIdx.x;
    const int l = tid & 63, w = tid >> 6;
    const int wr = w >> 1, wc = w & 1;

    f32x4 acc1[4][4], acc2[4][4];
    #pragma unroll
    for (int i = 0; i < 4; ++i)
        #pragma unroll
        for (int j = 0; j < 4; ++j) {
            acc1[i][j] = (f32x4){0.f,0.f,0.f,0.f};
            acc2[i][j] = (f32x4){0.f,0.f,0.f,0.f};
        }

    const char* Ar  = (const char*)ctxb + (size_t)m0*1536;
    const char* B1r = (const char*)wpb + (size_t)n0*1536;
    const char* B2r = (const char*)wpb + (size_t)(n0 + 128)*1536;
    char* Asb = (char*)As;
    char* B1b = (char*)B1;
    char* B2b = (char*)B2;
    const int co = 16 * ((l & 7) ^ (l >> 3));
    const size_t rstep = (size_t)(l >> 3) * 1536;
    const int rsw = (l & 7) << 4;

    for (int k0 = 0; k0 < 1536; k0 += 128) {
        #pragma unroll
        for (int i = 0; i < 4; ++i) {
            const int rb = i*32 + w*8;
            const size_t goff = (size_t)rb*1536 + rstep + k0 + co;
            gload_lds16(Ar  + goff, Asb + i*4096 + w*1024);
            gload_lds16(B1r + goff, B1b + i*4096 + w*1024);
            gload_lds16(B2r + goff, B2b + i*4096 + w*1024);
        }
        __syncthreads();
        #pragma unroll
        for (int kk = 0; kk < 2; ++kk) {
            const int coff = (kk*64 + ((l >> 4) << 4)) ^ rsw;
            bf16x8 af[4], b1[4], b2[4];
            #pragma unroll
            for (int mi = 0; mi < 4; ++mi) {
                const int rowA = wr*64 + mi*16 + (l & 15);
                af[mi] = *(const bf16x8*)(Asb + rowA*128 + coff);
                const int rowB = wc*64 + mi*16 + (l & 15);
                b1[mi] = *(const bf16x8*)(B1b + rowB*128 + coff);
                b2[mi] = *(const bf16x8*)(B2b + rowB*128 + coff);
            }
            #pragma unroll
            for (int mi = 0; mi < 4; ++mi)
                #pragma unroll
                for (int nj = 0; nj < 4; ++nj)
                    acc1[mi][nj] = __builtin_amdgcn_mfma_f32_16x16x32_bf16(
                                       af[mi], b1[nj], acc1[mi][nj], 0, 0, 0);
            #pragma unroll
            for (int mi = 0; mi < 4; ++mi)
                #pragma unroll
                for (int nj = 0; nj < 4; ++nj)
                    acc2[mi][nj] = __builtin_amdgcn_mfma_f32_16x16x32_bf16(
                                       af[mi], b2[nj], acc2[mi][nj], 0, 0, 0);
        }
        __syncthreads();
    }

    const int rbase = m0 + wr*64 + ((l >> 4) << 2);
    #pragma unroll
    for (int mi = 0; mi < 4; ++mi)
        #pragma unroll
        for (int nj = 0; nj < 4; ++nj) {
            const int col = n0 + wc*64 + nj*16 + (l & 15);
            const float bv = bias[col];
            #pragma unroll
            for (int rr = 0; rr < 4; ++rr) {
                const int m = rbase + mi*16 + rr;
                out[(size_t)m*768 + col] = acc1[mi][nj][rr] + bv;
            }
        }
    #pragma unroll
    for (int mi = 0; mi < 4; ++mi)
        #pragma unroll
        for (int nj = 0; nj < 4; ++nj) {
            const int col = n0 + 128 + wc*64 + nj*16 + (l & 15);
            const float bv = bias[col];
            #pragma unroll
            for (int rr = 0; rr < 4; ++rr) {
                const int m = rbase + mi*16 + rr;
                out[(size_t)m*768 + col] = acc2[mi][nj][rr] + bv;
            }
        }
}

// =======================================================================
// K2: K[n][m] = exp(10*cos(n,m) - 10) off-diag, 0 on diag. (R15-exact)
// =======================================================================
__global__ __launch_bounds__(256)
void cost_kernel(const u16* __restrict__ qnbf, u16* __restrict__ Kmat)
{
    __shared__ u16 Qa[128*64];     // [row][64 k] bf16, slot s holds global slot s^(row&7)
    __shared__ u16 Qb[128*64];
    const int bh = blockIdx.y;
    const int tr = (blockIdx.x >> 1) * 128;
    const int tc = (blockIdx.x & 1) * 128;
    const char* qb = (const char*)(qnbf + (size_t)bh * 16384);
    const int tid = threadIdx.x;
    const int l = tid & 63, w = tid >> 6;
    const int wr = w >> 1, wc = w & 1;

    {
        const int co = ((l & 7) ^ (l >> 3)) << 4;   // inverse-swizzled source slot
        const int rl = l >> 3;
        #pragma unroll
        for (int i = 0; i < 4; ++i) {
            const int ch = i*4 + w;                 // chunk 0..15
            gload_lds16(qb + (size_t)(tr + ch*8 + rl)*128 + co, (char*)Qa + ch*1024);
            gload_lds16(qb + (size_t)(tc + ch*8 + rl)*128 + co, (char*)Qb + ch*1024);
        }
    }
    __syncthreads();

    f32x4 acc[4][4];
    #pragma unroll
    for (int i = 0; i < 4; ++i)
        #pragma unroll
        for (int j = 0; j < 4; ++j) acc[i][j] = (f32x4){0.f,0.f,0.f,0.f};

    bf16x8 af[2][4], bfr[2][4];
    #pragma unroll
    for (int kk = 0; kk < 2; ++kk) {
        const int kb = kk*64 + ((l >> 4) << 4);
        #pragma unroll
        for (int f = 0; f < 4; ++f) {
            const int ra = wr*64 + f*16 + (l & 15);
            af[kk][f]  = *(const bf16x8*)((char*)Qa + ra*128 + (kb ^ ((ra & 7) << 4)));
            const int rb = wc*64 + f*16 + (l & 15);
            bfr[kk][f] = *(const bf16x8*)((char*)Qb + rb*128 + (kb ^ ((rb & 7) << 4)));
        }
    }
    #pragma unroll
    for (int mi = 0; mi < 4; ++mi)
        #pragma unroll
        for (int nj = 0; nj < 4; ++nj) {
            acc[mi][nj] = __builtin_amdgcn_mfma_f32_16x16x32_bf16(
                              af[0][mi], bfr[0][nj], acc[mi][nj], 0, 0, 0);
            acc[mi][nj] = __builtin_amdgcn_mfma_f32_16x16x32_bf16(
                              af[1][mi], bfr[1][nj], acc[mi][nj], 0, 0, 0);
        }

    u16* Kb = Kmat + (size_t)bh * 65536;
    #pragma unroll
    for (int mi = 0; mi < 4; ++mi)
        #pragma unroll
        for (int nj = 0; nj < 4; ++nj) {
            const int gr0 = tr + wr*64 + mi*16 + ((l >> 4) << 2);
            const int gc  = tc + wc*64 + nj*16 + (l & 15);
            #pragma unroll
            for (int rr = 0; rr < 4; ++rr) {
                const int gr = gr0 + rr;
                const float s = acc[mi][nj][rr];
                const float km = (gr == gc) ? 0.f : __expf(fmaf(10.f, s, -10.f));
                Kb[(size_t)gr * 256 + gc] = f2bf(km);
            }
        }
}

// =======================================================================
// K3 (split A): Sinkhorn iterations + Tmax only. (R15-exact)
// =======================================================================
__global__ __launch_bounds__(512, 2)
void sinkhorn_kernel(const u16* __restrict__ Kmat, float* __restrict__ ubuf,
                     float* __restrict__ vbuf, float* __restrict__ tmaxbuf)
{
    __shared__ __align__(16) float xv[256];
    __shared__ __align__(16) float usave[256];
    __shared__ __align__(16) u16   xbf[256];
    __shared__ float pmax[8];
    const int bh  = blockIdx.x;
    const int tid = threadIdx.x;
    const int l = tid & 63, w = tid >> 6;
    const int rowb = w * 32;
    const char* Kg = (const char*)(Kmat + (size_t)bh * 65536);

    bf16x8 kf[2][8];
    {
        const char* kb0 = Kg + (size_t)(rowb + (l & 15)) * 512 + ((l >> 4) << 4);
        #pragma unroll
        for (int t = 0; t < 2; ++t)
            #pragma unroll
            for (int ks = 0; ks < 8; ++ks)
                kf[t][ks] = *(const bf16x8*)(kb0 + t*8192 + ks*64);
    }
    if (tid < 256) xbf[tid] = 0x3f80;    // bf16(1.0)
    __syncthreads();

    for (int it = 0; it < 20; ++it) {
        f32x4 a0a = {0.f,0.f,0.f,0.f}, a0b = {0.f,0.f,0.f,0.f};
        f32x4 a1a = {0.f,0.f,0.f,0.f}, a1b = {0.f,0.f,0.f,0.f};
        #pragma unroll
        for (int ks = 0; ks < 4; ++ks) {
            const bf16x8 xf = *(const bf16x8*)((const char*)xbf + ks*64 + ((l >> 4) << 4));
            a0a = __builtin_amdgcn_mfma_f32_16x16x32_bf16(kf[0][ks], xf, a0a, 0, 0, 0);
            a1a = __builtin_amdgcn_mfma_f32_16x16x32_bf16(kf[1][ks], xf, a1a, 0, 0, 0);
        }
        #pragma unroll
        for (int ks = 4; ks < 8; ++ks) {
            const bf16x8 xf = *(const bf16x8*)((const char*)xbf + ks*64 + ((l >> 4) << 4));
            a0b = __builtin_amdgcn_mfma_f32_16x16x32_bf16(kf[0][ks], xf, a0b, 0, 0, 0);
            a1b = __builtin_amdgcn_mfma_f32_16x16x32_bf16(kf[1][ks], xf, a1b, 0, 0, 0);
        }
        float xn0[4], xn1[4];
        #pragma unroll
        for (int j = 0; j < 4; ++j) {
            xn0[j] = 0.00390625f * __builtin_amdgcn_rcpf(a0a[j] + a0b[j]);
            xn1[j] = 0.00390625f * __builtin_amdgcn_rcpf(a1a[j] + a1b[j]);
        }
        const u32 xp0 = cvtpk2bf(xn0[0], xn0[1]);
        const u32 xp1 = cvtpk2bf(xn0[2], xn0[3]);
        const u32 xp2 = cvtpk2bf(xn1[0], xn1[1]);
        const u32 xp3 = cvtpk2bf(xn1[2], xn1[3]);
        if ((l & 15) == 0) {
            const int r0 = rowb + ((l >> 4) << 2);
            *(uint2*)&xbf[r0]      = make_uint2(xp0, xp1);
            *(uint2*)&xbf[r0 + 16] = make_uint2(xp2, xp3);
            if (it == 18) {
                *(float4*)&usave[r0]      = make_float4(xn0[0], xn0[1], xn0[2], xn0[3]);
                *(float4*)&usave[r0 + 16] = make_float4(xn1[0], xn1[1], xn1[2], xn1[3]);
            }
            if (it == 19) {
                *(float4*)&xv[r0]      = make_float4(xn0[0], xn0[1], xn0[2], xn0[3]);
                *(float4*)&xv[r0 + 16] = make_float4(xn1[0], xn1[1], xn1[2], xn1[3]);
            }
        }
        __syncthreads();
    }

    {
        float mx0 = 0.f, mx1 = 0.f;
        #pragma unroll
        for (int ks = 0; ks < 8; ++ks) {
            const int mbase = ks*32 + ((l >> 4) << 3);
            const float4 va  = *(const float4*)&xv[mbase];
            const float4 vb4 = *(const float4*)&xv[mbase + 4];
            const float vv[8] = {va.x, va.y, va.z, va.w, vb4.x, vb4.y, vb4.z, vb4.w};
            #pragma unroll
            for (int j = 0; j < 8; ++j) {
                mx0 = fmaxf(mx0, bf2f((u16)kf[0][ks][j]) * vv[j]);
                mx1 = fmaxf(mx1, bf2f((u16)kf[1][ks][j]) * vv[j]);
            }
        }
        float mx = fmaxf(usave[rowb + (l & 15)] * mx0,
                         usave[rowb + 16 + (l & 15)] * mx1);
        #pragma unroll
        for (int off = 32; off > 0; off >>= 1) mx = fmaxf(mx, __shfl_xor(mx, off));
        if (l == 0) pmax[w] = mx;
    }
    __syncthreads();
    if (tid < 256) {
        ubuf[bh * 256 + tid] = usave[tid];
        vbuf[bh * 256 + tid] = xv[tid];
    }
    if (tid == 0) {
        float tm = pmax[0];
        #pragma unroll
        for (int i = 1; i < 8; ++i) tm = fmaxf(tm, pmax[i]);
        tmaxbuf[bh] = tm;
    }
}

// =======================================================================
// K4 (split B): P + PV. (R15-exact)
// =======================================================================
__global__ __launch_bounds__(512, 2)
void pv_kernel(const u16* __restrict__ Kmat, const u16* __restrict__ vbfT,
               const float* __restrict__ ubuf, const float* __restrict__ vbuf,
               const float* __restrict__ tmaxbuf, u16* __restrict__ ctxc)
{
    __shared__ u16 Vt[64*256];       // 32 KB, slot s of row d holds global slot s^(d&7)
    __shared__ __align__(16) float xv[256];
    const int bh  = blockIdx.x;
    const int b_ = bh / 12, h_ = bh - b_*12;
    const int tid = threadIdx.x;
    const int l = tid & 63, w = tid >> 6;
    const int rowb = w * 32;
    const char* Kg = (const char*)(Kmat + (size_t)bh * 65536);

    {
        const char* src = (const char*)(vbfT + (size_t)bh * 16384);
        char* dst = (char*)Vt;
        const int s = l & 31;
        #pragma unroll
        for (int i = 0; i < 4; ++i) {
            const int d = i*16 + w*2 + (l >> 5);
            gload_lds16(src + d*512 + ((s ^ (d & 7)) << 4), dst + i*8192 + w*1024);
        }
    }
    if (tid < 256) xv[tid] = vbuf[bh*256 + tid];

    bf16x8 kf[2][8];
    {
        const char* kb0 = Kg + (size_t)(rowb + (l & 15)) * 512 + ((l >> 4) << 4);
        #pragma unroll
        for (int t = 0; t < 2; ++t)
            #pragma unroll
            for (int ks = 0; ks < 8; ++ks)
                kf[t][ks] = *(const bf16x8*)(kb0 + t*8192 + ks*64);
    }
    const float itmax = 1.0f / tmaxbuf[bh];
    const float u0 = ubuf[bh*256 + rowb + (l & 15)];
    const float u1 = ubuf[bh*256 + rowb + 16 + (l & 15)];
    __syncthreads();                 // Vt + xv resident

    u16* outp = ctxc + ((size_t)b_*256)*768 + h_*64;
    #pragma unroll
    for (int t = 0; t < 2; ++t) {
        const int rown = rowb + t*16 + (l & 15);
        const float an = (t == 0 ? u0 : u1) * itmax * 0.125f;
        float psum = 0.f;
        f32x4 acc0 = {0.f,0.f,0.f,0.f}, acc1 = {0.f,0.f,0.f,0.f};
        f32x4 acc2 = {0.f,0.f,0.f,0.f}, acc3 = {0.f,0.f,0.f,0.f};
        #pragma unroll
        for (int ks = 0; ks < 8; ++ks) {
            const int mbase = ks*32 + ((l >> 4) << 3);
            const float4 va  = *(const float4*)&xv[mbase];
            const float4 vb4 = *(const float4*)&xv[mbase + 4];
            const float vv[8] = {va.x, va.y, va.z, va.w, vb4.x, vb4.y, vb4.z, vb4.w};
            float p[8];
            #pragma unroll
            for (int j = 0; j < 8; ++j)
                p[j] = __expf(an * bf2f((u16)kf[t][ks][j]) * vv[j]);
            const int dj = rown - mbase;
            if (dj >= 0 && dj < 8) p[dj] = 1.13314845f;     // exp(0.125)
            psum += ((p[0]+p[1]) + (p[2]+p[3])) + ((p[4]+p[5]) + (p[6]+p[7]));
            uint4 pwv = make_uint4(cvtpk2bf(p[0], p[1]), cvtpk2bf(p[2], p[3]),
                                   cvtpk2bf(p[4], p[5]), cvtpk2bf(p[6], p[7]));
            const bf16x8 pf = *(const bf16x8*)&pwv;
            const int bc = ks*64 + ((l >> 4) << 4);
            {
                const int d = (l & 15);
                const bf16x8 vf = *(const bf16x8*)((char*)Vt + d*512 + (bc ^ ((d & 7) << 4)));
                acc0 = __builtin_amdgcn_mfma_f32_16x16x32_bf16(vf, pf, acc0, 0, 0, 0);
            }
            {
                const int d = 16 + (l & 15);
                const bf16x8 vf = *(const bf16x8*)((char*)Vt + d*512 + (bc ^ ((d & 7) << 4)));
                acc1 = __builtin_amdgcn_mfma_f32_16x16x32_bf16(vf, pf, acc1, 0, 0, 0);
            }
            {
                const int d = 32 + (l & 15);
                const bf16x8 vf = *(const bf16x8*)((char*)Vt + d*512 + (bc ^ ((d & 7) << 4)));
                acc2 = __builtin_amdgcn_mfma_f32_16x16x32_bf16(vf, pf, acc2, 0, 0, 0);
            }
            {
                const int d = 48 + (l & 15);
                const bf16x8 vf = *(const bf16x8*)((char*)Vt + d*512 + (bc ^ ((d & 7) << 4)));
                acc3 = __builtin_amdgcn_mfma_f32_16x16x32_bf16(vf, pf, acc3, 0, 0, 0);
            }
        }
        psum += __shfl_xor(psum, 16);
        psum += __shfl_xor(psum, 32);                  // 4 lanes/row summed
        const float is = 1.0f / psum;
        const int d0 = (l >> 4) << 2;
        uint2 o0 = make_uint2(cvtpk2bf(acc0[0]*is, acc0[1]*is), cvtpk2bf(acc0[2]*is, acc0[3]*is));
        uint2 o1 = make_uint2(cvtpk2bf(acc1[0]*is, acc1[1]*is), cvtpk2bf(acc1[2]*is, acc1[3]*is));
        uint2 o2 = make_uint2(cvtpk2bf(acc2[0]*is, acc2[1]*is), cvtpk2bf(acc2[2]*is, acc2[3]*is));
        uint2 o3 = make_uint2(cvtpk2bf(acc3[0]*is, acc3[1]*is), cvtpk2bf(acc3[2]*is, acc3[3]*is));
        u16* orow = outp + (size_t)rown*768;
        *(uint2*)&orow[d0]      = o0;
        *(uint2*)&orow[16 + d0] = o1;
        *(uint2*)&orow[32 + d0] = o2;
        *(uint2*)&orow[48 + d0] = o3;
    }
}

// =======================================================================
extern "C" void kernel_launch(void* const* d_in, const int* in_sizes, int n_in,
                              void* d_out, int out_size, void* d_ws, size_t ws_size,
                              hipStream_t stream)
{
    (void)in_sizes; (void)n_in; (void)out_size; (void)ws_size;
    const float* x      = (const float*)d_in[0];
    const float* w_qkv  = (const float*)d_in[1];
    const float* w_proj = (const float*)d_in[2];
    const float* b_proj = (const float*)d_in[3];
    float* out = (float*)d_out;

    char* w = (char*)d_ws;
    // workspace layout (bytes):
    u16*   xbf  = (u16*)  (w);                     //  25,165,824  x bf16 [16384][768]
    u16*   wqv  = (u16*)  (w + 25165824);          //   2,359,296  w q+v rows bf16 [1536][768]
    u16*   wpb  = (u16*)  (w + 27525120);          //   1,179,648  w_proj bf16 [768][768]
    u16*   qnbf = (u16*)  (w + 28704768);          //  25,165,824  qn bf16 [768][256][64]
    u16*   vbfT = (u16*)  (w + 79036416);          //  25,165,824  v^T bf16 [768][64][256]
    u16*   ctxc = (u16*)  (w + 104202240);         //  25,165,824  ctx bf16 [64][256][768]
    float* ub   = (float*)(w + 129368064);         //     786,432  u [768][256]
    float* vb   = (float*)(w + 130154496);         //     786,432  v [768][256]
    float* tmx  = (float*)(w + 130940928);         //       3,072  tmax [768]
    u16*   Km   = (u16*)  (w + 130944000);         // 100,663,296  K bf16 [768][256][256]
    // total ~231.6 MB

    conv_all       <<<dim3(7008),    256, 0, stream>>>(x, w_qkv, w_proj, xbf, wqv, wpb);
    gemm_qkv_mfma  <<<dim3(128, 6),  256, 0, stream>>>(xbf, wqv, qnbf, vbfT);
    cost_kernel    <<<dim3(4, 768),  256, 0, stream>>>(qnbf, Km);
    sinkhorn_kernel<<<dim3(768),     512, 0, stream>>>(Km, ub, vb, tmx);
    pv_kernel      <<<dim3(768),     512, 0, stream>>>(Km, vbfT, ub, vb, tmx, ctxc);
    gemm_proj_mfma <<<dim3(128, 3),  256, 0, stream>>>(ctxc, wpb, b_proj, out);
}

// Round 18
// 198.455 us; speedup vs baseline: 1.1548x; 1.0223x over previous
//
#include <hip/hip_runtime.h>

typedef unsigned short u16;
typedef unsigned int   u32;
typedef __attribute__((ext_vector_type(8))) short bf16x8;
typedef __attribute__((ext_vector_type(4))) float f32x4;

// ---------- bf16 helpers (manual, RNE) ----------
__device__ __forceinline__ u16 f2bf(float f) {
    u32 u = __float_as_uint(f);
    u += 0x7fffu + ((u >> 16) & 1u);
    return (u16)(u >> 16);
}
__device__ __forceinline__ float bf2f(u16 s) {
    return __uint_as_float(((u32)s) << 16);
}
__device__ __forceinline__ u32 pack2bf(float f0, float f1) {
    return (u32)f2bf(f0) | ((u32)f2bf(f1) << 16);
}
// HW packed conversion (validated on P/ctx/x-iterate paths only — NOT
// upstream of the exp(10*cos-10) amplifier; see R13 post-mortem)
__device__ __forceinline__ u32 cvtpk2bf(float f0, float f1) {
    u32 r;
    asm("v_cvt_pk_bf16_f32 %0, %1, %2" : "=v"(r) : "v"(f0), "v"(f1));
    return r;
}

__device__ __forceinline__ void gload_lds16(const void* g, void* l) {
    __builtin_amdgcn_global_load_lds(
        (const __attribute__((address_space(1))) u32*)g,
        (__attribute__((address_space(3))) u32*)l, 16, 0, 0);
}

// =======================================================================
// Fused fp32 -> bf16 conversion for ALL three inputs (one launch).
// =======================================================================
__global__ __launch_bounds__(256)
void conv_all(const float* __restrict__ x, const float* __restrict__ wqkv,
              const float* __restrict__ wproj, u16* __restrict__ xbf,
              u16* __restrict__ wqv, u16* __restrict__ wpb)
{
    const int i = blockIdx.x * 256 + threadIdx.x;
    if (i < 1572864) {
        const float4 a = ((const float4*)x)[2*i];
        const float4 b = ((const float4*)x)[2*i + 1];
        ((uint4*)xbf)[i] = make_uint4(pack2bf(a.x,a.y), pack2bf(a.z,a.w),
                                      pack2bf(b.x,b.y), pack2bf(b.z,b.w));
    } else if (i < 1572864 + 147456) {
        const int j = i - 1572864;
        const int row = j / 96;
        const int cc  = (j - row * 96) * 8;
        const int srow = row + (row >= 768 ? 768 : 0);
        const float4 a = *(const float4*)&wqkv[(size_t)srow*768 + cc];
        const float4 b = *(const float4*)&wqkv[(size_t)srow*768 + cc + 4];
        *(uint4*)&wqv[(size_t)row*768 + cc] =
            make_uint4(pack2bf(a.x,a.y), pack2bf(a.z,a.w),
                       pack2bf(b.x,b.y), pack2bf(b.z,b.w));
    } else if (i < 1572864 + 147456 + 73728) {
        const int j = i - 1572864 - 147456;
        const float4 a = ((const float4*)wproj)[2*j];
        const float4 b = ((const float4*)wproj)[2*j + 1];
        ((uint4*)wpb)[j] = make_uint4(pack2bf(a.x,a.y), pack2bf(a.z,a.w),
                                      pack2bf(b.x,b.y), pack2bf(b.z,b.w));
    }
}

// =======================================================================
// K0 (widened tile): q+v projection + FUSED q-normalize, ONE block per
// (m0, bj in 0..5): A-tile staged ONCE per K-step, two B-panels, 64 MFMAs
// per K-step against 2 barriers. launch_bounds(256,3): 48KB LDS x 3 =
// 144KB <= 160KB -> 3 blocks/CU; grid 768 = 256 CU x 3 exactly (no tail).
// =======================================================================
__global__ __launch_bounds__(256, 3)
void gemm_qkv_mfma(const u16* __restrict__ xbf, const u16* __restrict__ wqv,
                   u16* __restrict__ qnbf, u16* __restrict__ vbfT)
{
    __shared__ u16 As[128*64];     // 16 KB  A panel (x rows)
    __shared__ u16 Bq[128*64];     // 16 KB  q-col panel (wqv rows bj*128..)
    __shared__ u16 Bv[128*64];     // 16 KB  v-col panel (wqv rows 768+bj*128..)
    const int m0 = blockIdx.x * 128;
    const int bj = blockIdx.y;                      // 0..5
    const int tid = threadIdx.x;
    const int l = tid & 63, w = tid >> 6;
    const int wr = w >> 1, wc = w & 1;

    f32x4 accq[4][4], accv[4][4];
    #pragma unroll
    for (int i = 0; i < 4; ++i)
        #pragma unroll
        for (int j = 0; j < 4; ++j) {
            accq[i][j] = (f32x4){0.f,0.f,0.f,0.f};
            accv[i][j] = (f32x4){0.f,0.f,0.f,0.f};
        }

    const char* Ar  = (const char*)xbf + (size_t)m0*1536;
    const char* Bqr = (const char*)wqv + (size_t)(bj*128)*1536;
    const char* Bvr = (const char*)wqv + (size_t)(768 + bj*128)*1536;
    char* Asb = (char*)As;
    char* Bqb = (char*)Bq;
    char* Bvb = (char*)Bv;
    const int co = 16 * ((l & 7) ^ (l >> 3));       // swizzled global byte col
    const size_t rstep = (size_t)(l >> 3) * 1536;
    const int rsw = (l & 7) << 4;                   // read-side XOR

    for (int k0 = 0; k0 < 1536; k0 += 128) {        // 12 K-steps of 64 bf16
        #pragma unroll
        for (int i = 0; i < 4; ++i) {
            const int rb = i*32 + w*8;
            const size_t goff = (size_t)rb*1536 + rstep + k0 + co;
            gload_lds16(Ar  + goff, Asb + i*4096 + w*1024);
            gload_lds16(Bqr + goff, Bqb + i*4096 + w*1024);
            gload_lds16(Bvr + goff, Bvb + i*4096 + w*1024);
        }
        __syncthreads();
        #pragma unroll
        for (int kk = 0; kk < 2; ++kk) {
            const int coff = (kk*64 + ((l >> 4) << 4)) ^ rsw;
            bf16x8 af[4], bq[4], bv[4];
            #pragma unroll
            for (int mi = 0; mi < 4; ++mi) {
                const int rowA = wr*64 + mi*16 + (l & 15);
                af[mi] = *(const bf16x8*)(Asb + rowA*128 + coff);
                const int rowB = wc*64 + mi*16 + (l & 15);
                bq[mi] = *(const bf16x8*)(Bqb + rowB*128 + coff);
                bv[mi] = *(const bf16x8*)(Bvb + rowB*128 + coff);
            }
            #pragma unroll
            for (int mi = 0; mi < 4; ++mi)
                #pragma unroll
                for (int nj = 0; nj < 4; ++nj)
                    accq[mi][nj] = __builtin_amdgcn_mfma_f32_16x16x32_bf16(
                                       af[mi], bq[nj], accq[mi][nj], 0, 0, 0);
            #pragma unroll
            for (int mi = 0; mi < 4; ++mi)
                #pragma unroll
                for (int nj = 0; nj < 4; ++nj)
                    accv[mi][nj] = __builtin_amdgcn_mfma_f32_16x16x32_bf16(
                                       af[mi], bv[nj], accv[mi][nj], 0, 0, 0);
        }
        __syncthreads();
    }

    const int rbase = m0 + wr*64 + ((l >> 4) << 2);
    // ---- q epilogue: fused normalize, h = 2*bj + wc
    {
        const int h = 2*bj + wc;                   // wave's 64 q-cols = head h
        #pragma unroll
        for (int mi = 0; mi < 4; ++mi)
            #pragma unroll
            for (int rr = 0; rr < 4; ++rr) {
                float s =      accq[mi][0][rr]*accq[mi][0][rr];
                s = fmaf(accq[mi][1][rr], accq[mi][1][rr], s);
                s = fmaf(accq[mi][2][rr], accq[mi][2][rr], s);
                s = fmaf(accq[mi][3][rr], accq[mi][3][rr], s);
                #pragma unroll
                for (int off = 1; off < 16; off <<= 1) s += __shfl_xor(s, off);
                const float inv = 1.0f / (sqrtf(s) + 1e-8f);
                const int m = rbase + mi*16 + rr;
                const int b_ = m >> 8, n_ = m & 255;
                u16* row = qnbf + ((((size_t)b_*12 + h) << 8) + n_)*64;
                #pragma unroll
                for (int nj = 0; nj < 4; ++nj)
                    row[nj*16 + (l & 15)] = f2bf(accq[mi][nj][rr] * inv);
            }
    }
    // ---- v epilogue: transposed bf16 store, colb = bj*128+wc*64
    {
        const int colb = bj*128 + wc*64;
        #pragma unroll
        for (int mi = 0; mi < 4; ++mi)
            #pragma unroll
            for (int nj = 0; nj < 4; ++nj) {
                const int col = colb + nj*16 + (l & 15);
                const int h = col >> 6, d = col & 63;
                const int m = rbase + mi*16;        // rows m..m+3 (consecutive)
                const int b_ = m >> 8, n_ = m & 255;
                uint2 o = make_uint2(pack2bf(accv[mi][nj][0], accv[mi][nj][1]),
                                     pack2bf(accv[mi][nj][2], accv[mi][nj][3]));
                *(uint2*)&vbfT[(((size_t)b_*12 + h)*64 + d)*256 + n_] = o;
            }
    }
}

// =======================================================================
// K5 (widened tile): out = ctx @ w_proj^T + b_proj. (R17-exact)
// =======================================================================
__global__ __launch_bounds__(256, 2)
void gemm_proj_mfma(const u16* __restrict__ ctxb, const u16* __restrict__ wpb,
                    const float* __restrict__ bias, float* __restrict__ out)
{
    __shared__ u16 As[128*64];     // 16 KB  ctx rows
    __shared__ u16 B1[128*64];     // 16 KB  wpb rows n0..
    __shared__ u16 B2[128*64];     // 16 KB  wpb rows n0+128..
    const int m0 = blockIdx.x * 128;
    const int n0 = blockIdx.y * 256;
    const int tid = threadIdx.x;
    const int l = tid & 63, w = tid >> 6;
    const int wr = w >> 1, wc = w & 1;

    f32x4 acc1[4][4], acc2[4][4];
    #pragma unroll
    for (int i = 0; i < 4; ++i)
        #pragma unroll
        for (int j = 0; j < 4; ++j) {
            acc1[i][j] = (f32x4){0.f,0.f,0.f,0.f};
            acc2[i][j] = (f32x4){0.f,0.f,0.f,0.f};
        }

    const char* Ar  = (const char*)ctxb + (size_t)m0*1536;
    const char* B1r = (const char*)wpb + (size_t)n0*1536;
    const char* B2r = (const char*)wpb + (size_t)(n0 + 128)*1536;
    char* Asb = (char*)As;
    char* B1b = (char*)B1;
    char* B2b = (char*)B2;
    const int co = 16 * ((l & 7) ^ (l >> 3));
    const size_t rstep = (size_t)(l >> 3) * 1536;
    const int rsw = (l & 7) << 4;

    for (int k0 = 0; k0 < 1536; k0 += 128) {
        #pragma unroll
        for (int i = 0; i < 4; ++i) {
            const int rb = i*32 + w*8;
            const size_t goff = (size_t)rb*1536 + rstep + k0 + co;
            gload_lds16(Ar  + goff, Asb + i*4096 + w*1024);
            gload_lds16(B1r + goff, B1b + i*4096 + w*1024);
            gload_lds16(B2r + goff, B2b + i*4096 + w*1024);
        }
        __syncthreads();
        #pragma unroll
        for (int kk = 0; kk < 2; ++kk) {
            const int coff = (kk*64 + ((l >> 4) << 4)) ^ rsw;
            bf16x8 af[4], b1[4], b2[4];
            #pragma unroll
            for (int mi = 0; mi < 4; ++mi) {
                const int rowA = wr*64 + mi*16 + (l & 15);
                af[mi] = *(const bf16x8*)(Asb + rowA*128 + coff);
                const int rowB = wc*64 + mi*16 + (l & 15);
                b1[mi] = *(const bf16x8*)(B1b + rowB*128 + coff);
                b2[mi] = *(const bf16x8*)(B2b + rowB*128 + coff);
            }
            #pragma unroll
            for (int mi = 0; mi < 4; ++mi)
                #pragma unroll
                for (int nj = 0; nj < 4; ++nj)
                    acc1[mi][nj] = __builtin_amdgcn_mfma_f32_16x16x32_bf16(
                                       af[mi], b1[nj], acc1[mi][nj], 0, 0, 0);
            #pragma unroll
            for (int mi = 0; mi < 4; ++mi)
                #pragma unroll
                for (int nj = 0; nj < 4; ++nj)
                    acc2[mi][nj] = __builtin_amdgcn_mfma_f32_16x16x32_bf16(
                                       af[mi], b2[nj], acc2[mi][nj], 0, 0, 0);
        }
        __syncthreads();
    }

    const int rbase = m0 + wr*64 + ((l >> 4) << 2);
    #pragma unroll
    for (int mi = 0; mi < 4; ++mi)
        #pragma unroll
        for (int nj = 0; nj < 4; ++nj) {
            const int col = n0 + wc*64 + nj*16 + (l & 15);
            const float bv = bias[col];
            #pragma unroll
            for (int rr = 0; rr < 4; ++rr) {
                const int m = rbase + mi*16 + rr;
                out[(size_t)m*768 + col] = acc1[mi][nj][rr] + bv;
            }
        }
    #pragma unroll
    for (int mi = 0; mi < 4; ++mi)
        #pragma unroll
        for (int nj = 0; nj < 4; ++nj) {
            const int col = n0 + 128 + wc*64 + nj*16 + (l & 15);
            const float bv = bias[col];
            #pragma unroll
            for (int rr = 0; rr < 4; ++rr) {
                const int m = rbase + mi*16 + rr;
                out[(size_t)m*768 + col] = acc2[mi][nj][rr] + bv;
            }
        }
}

// =======================================================================
// K2: K[n][m] = exp(10*cos(n,m) - 10) off-diag, 0 on diag. (R15-exact)
// =======================================================================
__global__ __launch_bounds__(256)
void cost_kernel(const u16* __restrict__ qnbf, u16* __restrict__ Kmat)
{
    __shared__ u16 Qa[128*64];     // [row][64 k] bf16, slot s holds global slot s^(row&7)
    __shared__ u16 Qb[128*64];
    const int bh = blockIdx.y;
    const int tr = (blockIdx.x >> 1) * 128;
    const int tc = (blockIdx.x & 1) * 128;
    const char* qb = (const char*)(qnbf + (size_t)bh * 16384);
    const int tid = threadIdx.x;
    const int l = tid & 63, w = tid >> 6;
    const int wr = w >> 1, wc = w & 1;

    {
        const int co = ((l & 7) ^ (l >> 3)) << 4;   // inverse-swizzled source slot
        const int rl = l >> 3;
        #pragma unroll
        for (int i = 0; i < 4; ++i) {
            const int ch = i*4 + w;                 // chunk 0..15
            gload_lds16(qb + (size_t)(tr + ch*8 + rl)*128 + co, (char*)Qa + ch*1024);
            gload_lds16(qb + (size_t)(tc + ch*8 + rl)*128 + co, (char*)Qb + ch*1024);
        }
    }
    __syncthreads();

    f32x4 acc[4][4];
    #pragma unroll
    for (int i = 0; i < 4; ++i)
        #pragma unroll
        for (int j = 0; j < 4; ++j) acc[i][j] = (f32x4){0.f,0.f,0.f,0.f};

    bf16x8 af[2][4], bfr[2][4];
    #pragma unroll
    for (int kk = 0; kk < 2; ++kk) {
        const int kb = kk*64 + ((l >> 4) << 4);
        #pragma unroll
        for (int f = 0; f < 4; ++f) {
            const int ra = wr*64 + f*16 + (l & 15);
            af[kk][f]  = *(const bf16x8*)((char*)Qa + ra*128 + (kb ^ ((ra & 7) << 4)));
            const int rb = wc*64 + f*16 + (l & 15);
            bfr[kk][f] = *(const bf16x8*)((char*)Qb + rb*128 + (kb ^ ((rb & 7) << 4)));
        }
    }
    #pragma unroll
    for (int mi = 0; mi < 4; ++mi)
        #pragma unroll
        for (int nj = 0; nj < 4; ++nj) {
            acc[mi][nj] = __builtin_amdgcn_mfma_f32_16x16x32_bf16(
                              af[0][mi], bfr[0][nj], acc[mi][nj], 0, 0, 0);
            acc[mi][nj] = __builtin_amdgcn_mfma_f32_16x16x32_bf16(
                              af[1][mi], bfr[1][nj], acc[mi][nj], 0, 0, 0);
        }

    u16* Kb = Kmat + (size_t)bh * 65536;
    #pragma unroll
    for (int mi = 0; mi < 4; ++mi)
        #pragma unroll
        for (int nj = 0; nj < 4; ++nj) {
            const int gr0 = tr + wr*64 + mi*16 + ((l >> 4) << 2);
            const int gc  = tc + wc*64 + nj*16 + (l & 15);
            #pragma unroll
            for (int rr = 0; rr < 4; ++rr) {
                const int gr = gr0 + rr;
                const float s = acc[mi][nj][rr];
                const float km = (gr == gc) ? 0.f : __expf(fmaf(10.f, s, -10.f));
                Kb[(size_t)gr * 256 + gc] = f2bf(km);
            }
        }
}

// =======================================================================
// K3 (split A): Sinkhorn iterations + Tmax only. (R15-exact)
// =======================================================================
__global__ __launch_bounds__(512, 2)
void sinkhorn_kernel(const u16* __restrict__ Kmat, float* __restrict__ ubuf,
                     float* __restrict__ vbuf, float* __restrict__ tmaxbuf)
{
    __shared__ __align__(16) float xv[256];
    __shared__ __align__(16) float usave[256];
    __shared__ __align__(16) u16   xbf[256];
    __shared__ float pmax[8];
    const int bh  = blockIdx.x;
    const int tid = threadIdx.x;
    const int l = tid & 63, w = tid >> 6;
    const int rowb = w * 32;
    const char* Kg = (const char*)(Kmat + (size_t)bh * 65536);

    bf16x8 kf[2][8];
    {
        const char* kb0 = Kg + (size_t)(rowb + (l & 15)) * 512 + ((l >> 4) << 4);
        #pragma unroll
        for (int t = 0; t < 2; ++t)
            #pragma unroll
            for (int ks = 0; ks < 8; ++ks)
                kf[t][ks] = *(const bf16x8*)(kb0 + t*8192 + ks*64);
    }
    if (tid < 256) xbf[tid] = 0x3f80;    // bf16(1.0)
    __syncthreads();

    for (int it = 0; it < 20; ++it) {
        f32x4 a0a = {0.f,0.f,0.f,0.f}, a0b = {0.f,0.f,0.f,0.f};
        f32x4 a1a = {0.f,0.f,0.f,0.f}, a1b = {0.f,0.f,0.f,0.f};
        #pragma unroll
        for (int ks = 0; ks < 4; ++ks) {
            const bf16x8 xf = *(const bf16x8*)((const char*)xbf + ks*64 + ((l >> 4) << 4));
            a0a = __builtin_amdgcn_mfma_f32_16x16x32_bf16(kf[0][ks], xf, a0a, 0, 0, 0);
            a1a = __builtin_amdgcn_mfma_f32_16x16x32_bf16(kf[1][ks], xf, a1a, 0, 0, 0);
        }
        #pragma unroll
        for (int ks = 4; ks < 8; ++ks) {
            const bf16x8 xf = *(const bf16x8*)((const char*)xbf + ks*64 + ((l >> 4) << 4));
            a0b = __builtin_amdgcn_mfma_f32_16x16x32_bf16(kf[0][ks], xf, a0b, 0, 0, 0);
            a1b = __builtin_amdgcn_mfma_f32_16x16x32_bf16(kf[1][ks], xf, a1b, 0, 0, 0);
        }
        float xn0[4], xn1[4];
        #pragma unroll
        for (int j = 0; j < 4; ++j) {
            xn0[j] = 0.00390625f * __builtin_amdgcn_rcpf(a0a[j] + a0b[j]);
            xn1[j] = 0.00390625f * __builtin_amdgcn_rcpf(a1a[j] + a1b[j]);
        }
        const u32 xp0 = cvtpk2bf(xn0[0], xn0[1]);
        const u32 xp1 = cvtpk2bf(xn0[2], xn0[3]);
        const u32 xp2 = cvtpk2bf(xn1[0], xn1[1]);
        const u32 xp3 = cvtpk2bf(xn1[2], xn1[3]);
        if ((l & 15) == 0) {
            const int r0 = rowb + ((l >> 4) << 2);
            *(uint2*)&xbf[r0]      = make_uint2(xp0, xp1);
            *(uint2*)&xbf[r0 + 16] = make_uint2(xp2, xp3);
            if (it == 18) {
                *(float4*)&usave[r0]      = make_float4(xn0[0], xn0[1], xn0[2], xn0[3]);
                *(float4*)&usave[r0 + 16] = make_float4(xn1[0], xn1[1], xn1[2], xn1[3]);
            }
            if (it == 19) {
                *(float4*)&xv[r0]      = make_float4(xn0[0], xn0[1], xn0[2], xn0[3]);
                *(float4*)&xv[r0 + 16] = make_float4(xn1[0], xn1[1], xn1[2], xn1[3]);
            }
        }
        __syncthreads();
    }

    {
        float mx0 = 0.f, mx1 = 0.f;
        #pragma unroll
        for (int ks = 0; ks < 8; ++ks) {
            const int mbase = ks*32 + ((l >> 4) << 3);
            const float4 va  = *(const float4*)&xv[mbase];
            const float4 vb4 = *(const float4*)&xv[mbase + 4];
            const float vv[8] = {va.x, va.y, va.z, va.w, vb4.x, vb4.y, vb4.z, vb4.w};
            #pragma unroll
            for (int j = 0; j < 8; ++j) {
                mx0 = fmaxf(mx0, bf2f((u16)kf[0][ks][j]) * vv[j]);
                mx1 = fmaxf(mx1, bf2f((u16)kf[1][ks][j]) * vv[j]);
            }
        }
        float mx = fmaxf(usave[rowb + (l & 15)] * mx0,
                         usave[rowb + 16 + (l & 15)] * mx1);
        #pragma unroll
        for (int off = 32; off > 0; off >>= 1) mx = fmaxf(mx, __shfl_xor(mx, off));
        if (l == 0) pmax[w] = mx;
    }
    __syncthreads();
    if (tid < 256) {
        ubuf[bh * 256 + tid] = usave[tid];
        vbuf[bh * 256 + tid] = xv[tid];
    }
    if (tid == 0) {
        float tm = pmax[0];
        #pragma unroll
        for (int i = 1; i < 8; ++i) tm = fmaxf(tm, pmax[i]);
        tmaxbuf[bh] = tm;
    }
}

// =======================================================================
// K4 (split B): P + PV. (R15-exact)
// =======================================================================
__global__ __launch_bounds__(512, 2)
void pv_kernel(const u16* __restrict__ Kmat, const u16* __restrict__ vbfT,
               const float* __restrict__ ubuf, const float* __restrict__ vbuf,
               const float* __restrict__ tmaxbuf, u16* __restrict__ ctxc)
{
    __shared__ u16 Vt[64*256];       // 32 KB, slot s of row d holds global slot s^(d&7)
    __shared__ __align__(16) float xv[256];
    const int bh  = blockIdx.x;
    const int b_ = bh / 12, h_ = bh - b_*12;
    const int tid = threadIdx.x;
    const int l = tid & 63, w = tid >> 6;
    const int rowb = w * 32;
    const char* Kg = (const char*)(Kmat + (size_t)bh * 65536);

    {
        const char* src = (const char*)(vbfT + (size_t)bh * 16384);
        char* dst = (char*)Vt;
        const int s = l & 31;
        #pragma unroll
        for (int i = 0; i < 4; ++i) {
            const int d = i*16 + w*2 + (l >> 5);
            gload_lds16(src + d*512 + ((s ^ (d & 7)) << 4), dst + i*8192 + w*1024);
        }
    }
    if (tid < 256) xv[tid] = vbuf[bh*256 + tid];

    bf16x8 kf[2][8];
    {
        const char* kb0 = Kg + (size_t)(rowb + (l & 15)) * 512 + ((l >> 4) << 4);
        #pragma unroll
        for (int t = 0; t < 2; ++t)
            #pragma unroll
            for (int ks = 0; ks < 8; ++ks)
                kf[t][ks] = *(const bf16x8*)(kb0 + t*8192 + ks*64);
    }
    const float itmax = 1.0f / tmaxbuf[bh];
    const float u0 = ubuf[bh*256 + rowb + (l & 15)];
    const float u1 = ubuf[bh*256 + rowb + 16 + (l & 15)];
    __syncthreads();                 // Vt + xv resident

    u16* outp = ctxc + ((size_t)b_*256)*768 + h_*64;
    #pragma unroll
    for (int t = 0; t < 2; ++t) {
        const int rown = rowb + t*16 + (l & 15);
        const float an = (t == 0 ? u0 : u1) * itmax * 0.125f;
        float psum = 0.f;
        f32x4 acc0 = {0.f,0.f,0.f,0.f}, acc1 = {0.f,0.f,0.f,0.f};
        f32x4 acc2 = {0.f,0.f,0.f,0.f}, acc3 = {0.f,0.f,0.f,0.f};
        #pragma unroll
        for (int ks = 0; ks < 8; ++ks) {
            const int mbase = ks*32 + ((l >> 4) << 3);
            const float4 va  = *(const float4*)&xv[mbase];
            const float4 vb4 = *(const float4*)&xv[mbase + 4];
            const float vv[8] = {va.x, va.y, va.z, va.w, vb4.x, vb4.y, vb4.z, vb4.w};
            float p[8];
            #pragma unroll
            for (int j = 0; j < 8; ++j)
                p[j] = __expf(an * bf2f((u16)kf[t][ks][j]) * vv[j]);
            const int dj = rown - mbase;
            if (dj >= 0 && dj < 8) p[dj] = 1.13314845f;     // exp(0.125)
            psum += ((p[0]+p[1]) + (p[2]+p[3])) + ((p[4]+p[5]) + (p[6]+p[7]));
            uint4 pwv = make_uint4(cvtpk2bf(p[0], p[1]), cvtpk2bf(p[2], p[3]),
                                   cvtpk2bf(p[4], p[5]), cvtpk2bf(p[6], p[7]));
            const bf16x8 pf = *(const bf16x8*)&pwv;
            const int bc = ks*64 + ((l >> 4) << 4);
            {
                const int d = (l & 15);
                const bf16x8 vf = *(const bf16x8*)((char*)Vt + d*512 + (bc ^ ((d & 7) << 4)));
                acc0 = __builtin_amdgcn_mfma_f32_16x16x32_bf16(vf, pf, acc0, 0, 0, 0);
            }
            {
                const int d = 16 + (l & 15);
                const bf16x8 vf = *(const bf16x8*)((char*)Vt + d*512 + (bc ^ ((d & 7) << 4)));
                acc1 = __builtin_amdgcn_mfma_f32_16x16x32_bf16(vf, pf, acc1, 0, 0, 0);
            }
            {
                const int d = 32 + (l & 15);
                const bf16x8 vf = *(const bf16x8*)((char*)Vt + d*512 + (bc ^ ((d & 7) << 4)));
                acc2 = __builtin_amdgcn_mfma_f32_16x16x32_bf16(vf, pf, acc2, 0, 0, 0);
            }
            {
                const int d = 48 + (l & 15);
                const bf16x8 vf = *(const bf16x8*)((char*)Vt + d*512 + (bc ^ ((d & 7) << 4)));
                acc3 = __builtin_amdgcn_mfma_f32_16x16x32_bf16(vf, pf, acc3, 0, 0, 0);
            }
        }
        psum += __shfl_xor(psum, 16);
        psum += __shfl_xor(psum, 32);                  // 4 lanes/row summed
        const float is = 1.0f / psum;
        const int d0 = (l >> 4) << 2;
        uint2 o0 = make_uint2(cvtpk2bf(acc0[0]*is, acc0[1]*is), cvtpk2bf(acc0[2]*is, acc0[3]*is));
        uint2 o1 = make_uint2(cvtpk2bf(acc1[0]*is, acc1[1]*is), cvtpk2bf(acc1[2]*is, acc1[3]*is));
        uint2 o2 = make_uint2(cvtpk2bf(acc2[0]*is, acc2[1]*is), cvtpk2bf(acc2[2]*is, acc2[3]*is));
        uint2 o3 = make_uint2(cvtpk2bf(acc3[0]*is, acc3[1]*is), cvtpk2bf(acc3[2]*is, acc3[3]*is));
        u16* orow = outp + (size_t)rown*768;
        *(uint2*)&orow[d0]      = o0;
        *(uint2*)&orow[16 + d0] = o1;
        *(uint2*)&orow[32 + d0] = o2;
        *(uint2*)&orow[48 + d0] = o3;
    }
}

// =======================================================================
extern "C" void kernel_launch(void* const* d_in, const int* in_sizes, int n_in,
                              void* d_out, int out_size, void* d_ws, size_t ws_size,
                              hipStream_t stream)
{
    (void)in_sizes; (void)n_in; (void)out_size; (void)ws_size;
    const float* x      = (const float*)d_in[0];
    const float* w_qkv  = (const float*)d_in[1];
    const float* w_proj = (const float*)d_in[2];
    const float* b_proj = (const float*)d_in[3];
    float* out = (float*)d_out;

    char* w = (char*)d_ws;
    // workspace layout (bytes):
    u16*   xbf  = (u16*)  (w);                     //  25,165,824  x bf16 [16384][768]
    u16*   wqv  = (u16*)  (w + 25165824);          //   2,359,296  w q+v rows bf16 [1536][768]
    u16*   wpb  = (u16*)  (w + 27525120);          //   1,179,648  w_proj bf16 [768][768]
    u16*   qnbf = (u16*)  (w + 28704768);          //  25,165,824  qn bf16 [768][256][64]
    u16*   vbfT = (u16*)  (w + 79036416);          //  25,165,824  v^T bf16 [768][64][256]
    u16*   ctxc = (u16*)  (w + 104202240);         //  25,165,824  ctx bf16 [64][256][768]
    float* ub   = (float*)(w + 129368064);         //     786,432  u [768][256]
    float* vb   = (float*)(w + 130154496);         //     786,432  v [768][256]
    float* tmx  = (float*)(w + 130940928);         //       3,072  tmax [768]
    u16*   Km   = (u16*)  (w + 130944000);         // 100,663,296  K bf16 [768][256][256]
    // total ~231.6 MB

    conv_all       <<<dim3(7008),    256, 0, stream>>>(x, w_qkv, w_proj, xbf, wqv, wpb);
    gemm_qkv_mfma  <<<dim3(128, 6),  256, 0, stream>>>(xbf, wqv, qnbf, vbfT);
    cost_kernel    <<<dim3(4, 768),  256, 0, stream>>>(qnbf, Km);
    sinkhorn_kernel<<<dim3(768),     512, 0, stream>>>(Km, ub, vb, tmx);
    pv_kernel      <<<dim3(768),     512, 0, stream>>>(Km, vbfT, ub, vb, tmx, ctxc);
    gemm_proj_mfma <<<dim3(128, 3),  256, 0, stream>>>(ctxc, wpb, b_proj, out);
}